// Round 1
// baseline (1080.222 us; speedup 1.0000x reference)
//
#include <hip/hip_runtime.h>
#include <math.h>

#define NN 10000
#define EE 160000

// ---- workspace layout (floats) ----
// WtT   [6][64][64]  (WtT[k][c][d] = Wt_k[d][c])           @ 0        len 24576
// WsT   Ws0T[32][64] | Ws1T[64][128] | Ws2T[128][192]      @ 24576    len 34816
// Xn    [N][64][9]                                          @ 59392    len 5760000
// IAS   [N][9][64]   comps: I,a01,a02,a12,s00,s11,s01,s02,s12 @ 5819392 len 5760000
// Msg   [N][9][64]                                          @ 11579392 len 5760000
// ea    [E][192]                                            @ 17339392 len 30720000
// ints  counts[N] cursor[N] offsets[N+1] bucket[E]          @ 48059392 (as int*)
#define OFF_WTT 0
#define OFF_WST 24576
#define OFF_XN  59392
#define OFF_IAS 5819392
#define OFF_MSG 11579392
#define OFF_EA  17339392
#define OFF_INT 48059392

__device__ __forceinline__ float silu_f(float x) { return x / (1.0f + __expf(-x)); }

// ---------------- weight transpose ----------------
__global__ void k_transpose(const float* __restrict__ Wt0, const float* __restrict__ Wt1,
                            const float* __restrict__ Wt2, const float* __restrict__ Wt3,
                            const float* __restrict__ Wt4, const float* __restrict__ Wt5,
                            const float* __restrict__ Ws0, const float* __restrict__ Ws1,
                            const float* __restrict__ Ws2, float* __restrict__ dst) {
    int idx = blockIdx.x * 256 + threadIdx.x;
    if (idx < 24576) {
        int k = idx >> 12, r = idx & 4095;
        int c = r >> 6, d = r & 63;
        const float* W = (k == 0) ? Wt0 : (k == 1) ? Wt1 : (k == 2) ? Wt2
                       : (k == 3) ? Wt3 : (k == 4) ? Wt4 : Wt5;
        dst[idx] = W[d * 64 + c];
    } else if (idx < 26624) {          // Ws0T [32][64]
        int r = idx - 24576; int i = r >> 6, o = r & 63;
        dst[idx] = Ws0[o * 32 + i];
    } else if (idx < 34816) {          // Ws1T [64][128]
        int r = idx - 26624; int i = r >> 7, o = r & 127;
        dst[idx] = Ws1[o * 64 + i];
    } else if (idx < 59392) {          // Ws2T [128][192]
        int r = idx - 34816; int i = r / 192, o = r % 192;
        dst[idx] = Ws2[o * 128 + i];
    }
}

// ---------------- node prep: normalize, decompose, channel-linear ----------------
__global__ __launch_bounds__(64) void k_nodeprep(const float* __restrict__ X,
                                                 const float* __restrict__ WtT,
                                                 float* __restrict__ Xn,
                                                 float* __restrict__ IAS) {
    int n = blockIdx.x, c = threadIdx.x;
    __shared__ float L[64][10];
    const float* xp = X + (size_t)n * 576 + c * 9;
    float x[9];
#pragma unroll
    for (int i = 0; i < 9; i++) x[i] = xp[i];
    float nrm = 0.f;
#pragma unroll
    for (int i = 0; i < 9; i++) nrm += x[i] * x[i];
    float inv = 1.0f / (nrm + 1.0f);
#pragma unroll
    for (int i = 0; i < 9; i++) x[i] *= inv;
    float* xnp = Xn + (size_t)n * 576 + c * 9;
#pragma unroll
    for (int i = 0; i < 9; i++) xnp[i] = x[i];
    float tr3 = (x[0] + x[4] + x[8]) * (1.0f / 3.0f);
    L[c][0] = tr3;
    L[c][1] = 0.5f * (x[1] - x[3]);
    L[c][2] = 0.5f * (x[2] - x[6]);
    L[c][3] = 0.5f * (x[5] - x[7]);
    L[c][4] = x[0] - tr3;
    L[c][5] = x[4] - tr3;
    L[c][6] = 0.5f * (x[1] + x[3]);
    L[c][7] = 0.5f * (x[2] + x[6]);
    L[c][8] = 0.5f * (x[5] + x[7]);
    __syncthreads();
    int d = c;
    const float* W0 = WtT;             // Wt0T
    const float* W1 = WtT + 4096;      // Wt1T
    const float* W2 = WtT + 8192;      // Wt2T
    float aI = 0, aA0 = 0, aA1 = 0, aA2 = 0, aS0 = 0, aS1 = 0, aS2 = 0, aS3 = 0, aS4 = 0;
    for (int cc = 0; cc < 64; ++cc) {
        float w0 = W0[cc * 64 + d], w1 = W1[cc * 64 + d], w2 = W2[cc * 64 + d];
        aI  += w0 * L[cc][0];
        aA0 += w1 * L[cc][1]; aA1 += w1 * L[cc][2]; aA2 += w1 * L[cc][3];
        aS0 += w2 * L[cc][4]; aS1 += w2 * L[cc][5]; aS2 += w2 * L[cc][6];
        aS3 += w2 * L[cc][7]; aS4 += w2 * L[cc][8];
    }
    float* op = IAS + (size_t)n * 576;
    op[0 * 64 + d] = aI;
    op[1 * 64 + d] = aA0; op[2 * 64 + d] = aA1; op[3 * 64 + d] = aA2;
    op[4 * 64 + d] = aS0; op[5 * 64 + d] = aS1; op[6 * 64 + d] = aS2;
    op[7 * 64 + d] = aS3; op[8 * 64 + d] = aS4;
}

// ---------------- edge MLP (64 edges / block, 256 threads) ----------------
__global__ __launch_bounds__(256) void k_mlp(const float* __restrict__ attr,
                                             const float* __restrict__ ew,
                                             const float* __restrict__ WsT,
                                             const float* __restrict__ bs0,
                                             const float* __restrict__ bs1,
                                             const float* __restrict__ bs2,
                                             float* __restrict__ ea) {
    int e0 = blockIdx.x * 64;
    int t = threadIdx.x;
    __shared__ float a_s[64][33];
    __shared__ float h1[64][65];
    __shared__ float h2[64][129];
    __shared__ float Cs[64];
    for (int i = t; i < 64 * 32; i += 256) {
        int e = i >> 5, k = i & 31;
        a_s[e][k] = attr[(size_t)(e0 + e) * 32 + k];
    }
    if (t < 64) {
        float r = ew[e0 + t];
        Cs[t] = (r < 1.0f) ? 0.5f * (cosf(3.14159265358979f * r) + 1.0f) : 0.0f;
    }
    __syncthreads();
    int e = t & 63, og = t >> 6;
    const float* W0T = WsT;            // [32][64]
    const float* W1T = WsT + 2048;     // [64][128]
    const float* W2T = WsT + 10240;    // [128][192]
    // layer 1: 32 -> 64
    for (int ch = 0; ch < 4; ++ch) {
        int o = (ch * 4 + og) * 4;
        float a0 = bs0[o], a1 = bs0[o + 1], a2 = bs0[o + 2], a3 = bs0[o + 3];
#pragma unroll
        for (int k = 0; k < 32; ++k) {
            float4 w = *(const float4*)&W0T[k * 64 + o];
            float xv = a_s[e][k];
            a0 += xv * w.x; a1 += xv * w.y; a2 += xv * w.z; a3 += xv * w.w;
        }
        h1[e][o] = silu_f(a0); h1[e][o + 1] = silu_f(a1);
        h1[e][o + 2] = silu_f(a2); h1[e][o + 3] = silu_f(a3);
    }
    __syncthreads();
    // layer 2: 64 -> 128
    for (int ch = 0; ch < 8; ++ch) {
        int o = (ch * 4 + og) * 4;
        float a0 = bs1[o], a1 = bs1[o + 1], a2 = bs1[o + 2], a3 = bs1[o + 3];
#pragma unroll
        for (int k = 0; k < 64; ++k) {
            float4 w = *(const float4*)&W1T[k * 128 + o];
            float xv = h1[e][k];
            a0 += xv * w.x; a1 += xv * w.y; a2 += xv * w.z; a3 += xv * w.w;
        }
        h2[e][o] = silu_f(a0); h2[e][o + 1] = silu_f(a1);
        h2[e][o + 2] = silu_f(a2); h2[e][o + 3] = silu_f(a3);
    }
    __syncthreads();
    // layer 3: 128 -> 192, scale by C, write
    float Ce = Cs[e];
    for (int ch = 0; ch < 12; ++ch) {
        int o = (ch * 4 + og) * 4;
        float a0 = bs2[o], a1 = bs2[o + 1], a2 = bs2[o + 2], a3 = bs2[o + 3];
#pragma unroll
        for (int k = 0; k < 128; ++k) {
            float4 w = *(const float4*)&W2T[k * 192 + o];
            float xv = h2[e][k];
            a0 += xv * w.x; a1 += xv * w.y; a2 += xv * w.z; a3 += xv * w.w;
        }
        float4 r;
        r.x = silu_f(a0) * Ce; r.y = silu_f(a1) * Ce;
        r.z = silu_f(a2) * Ce; r.w = silu_f(a3) * Ce;
        *(float4*)&ea[(size_t)(e0 + e) * 192 + o] = r;
    }
}

// ---------------- CSR build ----------------
__global__ void k_count(const int* __restrict__ ei, int* __restrict__ counts) {
    int e = blockIdx.x * 256 + threadIdx.x;
    if (e < EE) atomicAdd(&counts[ei[e]], 1);
}

__global__ __launch_bounds__(256) void k_scan(const int* __restrict__ counts,
                                              int* __restrict__ offsets) {
    __shared__ int sums[256];
    int t = threadIdx.x;
    const int CH = 40;  // 256*40 >= NN
    int base = t * CH;
    int s = 0;
    for (int i = 0; i < CH; i++) {
        int idx = base + i;
        if (idx < NN) s += counts[idx];
    }
    sums[t] = s;
    __syncthreads();
    for (int off = 1; off < 256; off <<= 1) {
        int tmp = (t >= off) ? sums[t - off] : 0;
        __syncthreads();
        sums[t] += tmp;
        __syncthreads();
    }
    int run = sums[t] - s;  // exclusive prefix of this chunk
    for (int i = 0; i < CH; i++) {
        int idx = base + i;
        if (idx < NN) { offsets[idx] = run; run += counts[idx]; }
    }
    if (t == 255) offsets[NN] = run;
}

__global__ void k_fill(const int* __restrict__ ei, const int* __restrict__ offsets,
                       int* __restrict__ cursor, int* __restrict__ bucket) {
    int e = blockIdx.x * 256 + threadIdx.x;
    if (e < EE) {
        int s = ei[e];
        int pos = offsets[s] + atomicAdd(&cursor[s], 1);
        bucket[pos] = e;
    }
}

// ---------------- message aggregation (1 wave / node) ----------------
__global__ __launch_bounds__(64) void k_agg(const int* __restrict__ ei,
                                            const int* __restrict__ offsets,
                                            const int* __restrict__ bucket,
                                            const float* __restrict__ ea,
                                            const float* __restrict__ IAS,
                                            float* __restrict__ Msg) {
    int n = blockIdx.x, c = threadIdx.x;
    int beg = offsets[n], end = offsets[n + 1];
    float mI = 0, mA0 = 0, mA1 = 0, mA2 = 0, mS0 = 0, mS1 = 0, mS2 = 0, mS3 = 0, mS4 = 0;
    for (int i = beg; i < end; ++i) {
        int eid = bucket[i];
        int dst = ei[EE + eid];
        const float* eap = ea + (size_t)eid * 192 + 3 * c;
        float e0 = eap[0], e1 = eap[1], e2 = eap[2];
        const float* ip = IAS + (size_t)dst * 576;
        mI  += e0 * ip[c];
        mA0 += e1 * ip[64 + c];  mA1 += e1 * ip[128 + c]; mA2 += e1 * ip[192 + c];
        mS0 += e2 * ip[256 + c]; mS1 += e2 * ip[320 + c]; mS2 += e2 * ip[384 + c];
        mS3 += e2 * ip[448 + c]; mS4 += e2 * ip[512 + c];
    }
    float* mp = Msg + (size_t)n * 576;
    mp[c] = mI;
    mp[64 + c] = mA0;  mp[128 + c] = mA1; mp[192 + c] = mA2;
    mp[256 + c] = mS0; mp[320 + c] = mS1; mp[384 + c] = mS2;
    mp[448 + c] = mS3; mp[512 + c] = mS4;
}

// ---------------- output stage ----------------
__global__ __launch_bounds__(64) void k_out(const float* __restrict__ Msg,
                                            const float* __restrict__ IAS,
                                            const float* __restrict__ Xn,
                                            const float* __restrict__ WtT,
                                            float* __restrict__ out) {
    int n = blockIdx.x, c = threadIdx.x;
    __shared__ float L[64][10];
    const float* mp = Msg + (size_t)n * 576;
    const float* ip = IAS + (size_t)n * 576;
    float mI = mp[c], mA0 = mp[64 + c], mA1 = mp[128 + c], mA2 = mp[192 + c];
    float mS0 = mp[256 + c], mS1 = mp[320 + c], mS2 = mp[384 + c], mS3 = mp[448 + c], mS4 = mp[512 + c];
    float yI = ip[c], yA0 = ip[64 + c], yA1 = ip[128 + c], yA2 = ip[192 + c];
    float yS0 = ip[256 + c], yS1 = ip[320 + c], yS2 = ip[384 + c], yS3 = ip[448 + c], yS4 = ip[512 + c];
    float M[3][3] = {
        { mI + mS0,   mA0 + mS2,  mA1 + mS3 },
        { -mA0 + mS2, mI + mS1,   mA2 + mS4 },
        { -mA1 + mS3, -mA2 + mS4, mI - mS0 - mS1 } };
    float Y[3][3] = {
        { yI + yS0,   yA0 + yS2,  yA1 + yS3 },
        { -yA0 + yS2, yI + yS1,   yA2 + yS4 },
        { -yA1 + yS3, -yA2 + yS4, yI - yS0 - yS1 } };
    float AB[3][3];
#pragma unroll
    for (int i = 0; i < 3; i++)
#pragma unroll
        for (int j = 0; j < 3; j++) {
            float s = 0.f;
#pragma unroll
            for (int k = 0; k < 3; k++) s += M[i][k] * Y[k][j] + Y[i][k] * M[k][j];
            AB[i][j] = s;
        }
    float tr3 = (AB[0][0] + AB[1][1] + AB[2][2]) * (1.0f / 3.0f);
    float fro = 0.f;
#pragma unroll
    for (int i = 0; i < 3; i++)
#pragma unroll
        for (int j = 0; j < 3; j++) fro += AB[i][j] * AB[i][j];
    float inv = 1.0f / (fro + 1.0f);
    L[c][0] = tr3 * inv;
    L[c][1] = 0.5f * (AB[0][1] - AB[1][0]) * inv;
    L[c][2] = 0.5f * (AB[0][2] - AB[2][0]) * inv;
    L[c][3] = 0.5f * (AB[1][2] - AB[2][1]) * inv;
    L[c][4] = (AB[0][0] - tr3) * inv;
    L[c][5] = (AB[1][1] - tr3) * inv;
    L[c][6] = 0.5f * (AB[0][1] + AB[1][0]) * inv;
    L[c][7] = 0.5f * (AB[0][2] + AB[2][0]) * inv;
    L[c][8] = 0.5f * (AB[1][2] + AB[2][1]) * inv;
    __syncthreads();
    int d = c;
    const float* W3 = WtT + 3 * 4096;
    const float* W4 = WtT + 4 * 4096;
    const float* W5 = WtT + 5 * 4096;
    float aI = 0, aA0 = 0, aA1 = 0, aA2 = 0, aS0 = 0, aS1 = 0, aS2 = 0, aS3 = 0, aS4 = 0;
    for (int cc = 0; cc < 64; ++cc) {
        float w3 = W3[cc * 64 + d], w4 = W4[cc * 64 + d], w5 = W5[cc * 64 + d];
        aI  += w3 * L[cc][0];
        aA0 += w4 * L[cc][1]; aA1 += w4 * L[cc][2]; aA2 += w4 * L[cc][3];
        aS0 += w5 * L[cc][4]; aS1 += w5 * L[cc][5]; aS2 += w5 * L[cc][6];
        aS3 += w5 * L[cc][7]; aS4 += w5 * L[cc][8];
    }
    float dX[3][3] = {
        { aI + aS0,   aA0 + aS2,  aA1 + aS3 },
        { -aA0 + aS2, aI + aS1,   aA2 + aS4 },
        { -aA1 + aS3, -aA2 + aS4, aI - aS0 - aS1 } };
    float D2[3][3];
#pragma unroll
    for (int i = 0; i < 3; i++)
#pragma unroll
        for (int j = 0; j < 3; j++) {
            float s = 0.f;
#pragma unroll
            for (int k = 0; k < 3; k++) s += dX[i][k] * dX[k][j];
            D2[i][j] = s;
        }
    const float* xp = Xn + (size_t)n * 576 + d * 9;
    float* op = out + (size_t)n * 576 + d * 9;
#pragma unroll
    for (int i = 0; i < 3; i++)
#pragma unroll
        for (int j = 0; j < 3; j++) op[i * 3 + j] = xp[i * 3 + j] + dX[i][j] + D2[i][j];
}

extern "C" void kernel_launch(void* const* d_in, const int* in_sizes, int n_in,
                              void* d_out, int out_size, void* d_ws, size_t ws_size,
                              hipStream_t stream) {
    (void)in_sizes; (void)n_in; (void)out_size; (void)ws_size;
    const int* ei = (const int*)d_in[0];
    const float* ew = (const float*)d_in[1];
    const float* attr = (const float*)d_in[2];
    const float* X = (const float*)d_in[3];
    const float* Ws0 = (const float*)d_in[4];
    const float* bs0 = (const float*)d_in[5];
    const float* Ws1 = (const float*)d_in[6];
    const float* bs1 = (const float*)d_in[7];
    const float* Ws2 = (const float*)d_in[8];
    const float* bs2 = (const float*)d_in[9];
    const float* Wt0 = (const float*)d_in[10];
    const float* Wt1 = (const float*)d_in[11];
    const float* Wt2 = (const float*)d_in[12];
    const float* Wt3 = (const float*)d_in[13];
    const float* Wt4 = (const float*)d_in[14];
    const float* Wt5 = (const float*)d_in[15];
    float* ws = (float*)d_ws;
    int* ibase = (int*)(ws + OFF_INT);
    int* counts = ibase;
    int* cursor = ibase + NN;
    int* offsets = ibase + 2 * NN;
    int* bucket = ibase + 3 * NN + 1;

    hipMemsetAsync(counts, 0, 2 * NN * sizeof(int), stream);
    k_transpose<<<232, 256, 0, stream>>>(Wt0, Wt1, Wt2, Wt3, Wt4, Wt5, Ws0, Ws1, Ws2, ws);
    k_nodeprep<<<NN, 64, 0, stream>>>(X, ws, ws + OFF_XN, ws + OFF_IAS);
    k_mlp<<<EE / 64, 256, 0, stream>>>(attr, ew, ws + OFF_WST, bs0, bs1, bs2, ws + OFF_EA);
    k_count<<<(EE + 255) / 256, 256, 0, stream>>>(ei, counts);
    k_scan<<<1, 256, 0, stream>>>(counts, offsets);
    k_fill<<<(EE + 255) / 256, 256, 0, stream>>>(ei, offsets, cursor, bucket);
    k_agg<<<NN, 64, 0, stream>>>(ei, offsets, bucket, ws + OFF_EA, ws + OFF_IAS, ws + OFF_MSG);
    k_out<<<NN, 64, 0, stream>>>(ws + OFF_MSG, ws + OFF_IAS, ws + OFF_XN, ws, (float*)d_out);
}

// Round 2
// 237.621 us; speedup vs baseline: 4.5460x; 4.5460x over previous
//
#include <hip/hip_runtime.h>
#include <math.h>

#define NN 10000
#define EE 160000

// ---- workspace layout (floats) ----
// WtT   [6][64][64]  (WtT[k][c][d] = Wt_k[d][c])           @ 0        len 24576
// PK    packed bf16 MLP weights (34816 u16 = 17408 f32)     @ 24576
// Xn    [N][64][9]                                          @ 59392    len 5760000
// IAS   [N][9][64]                                          @ 5819392  len 5760000
// Msg   [N][9][64]                                          @ 11579392 len 5760000
// ea    [E][192]                                            @ 17339392 len 30720000
// ints  counts[N] cursor[N] offsets[N+1] bucket[E]          @ 48059392 (as int*)
#define OFF_WTT 0
#define OFF_PK  24576
#define OFF_XN  59392
#define OFF_IAS 5819392
#define OFF_MSG 11579392
#define OFF_EA  17339392
#define OFF_INT 48059392

typedef __attribute__((ext_vector_type(8))) short bf16x8;
typedef __attribute__((ext_vector_type(4))) float f32x4;

__device__ __forceinline__ float silu_f(float x) { return x / (1.0f + __expf(-x)); }

__device__ __forceinline__ unsigned short f2bf(float f) {
    unsigned int u = __float_as_uint(f);
    unsigned int r = (u + 0x7FFFu + ((u >> 16) & 1u)) >> 16;
    return (unsigned short)r;
}

// ---------------- weight transpose (node-side Wt only) ----------------
__global__ void k_transpose(const float* __restrict__ Wt0, const float* __restrict__ Wt1,
                            const float* __restrict__ Wt2, const float* __restrict__ Wt3,
                            const float* __restrict__ Wt4, const float* __restrict__ Wt5,
                            float* __restrict__ dst) {
    int idx = blockIdx.x * 256 + threadIdx.x;
    if (idx < 24576) {
        int k = idx >> 12, r = idx & 4095;
        int c = r >> 6, d = r & 63;
        const float* W = (k == 0) ? Wt0 : (k == 1) ? Wt1 : (k == 2) ? Wt2
                       : (k == 3) ? Wt3 : (k == 4) ? Wt4 : Wt5;
        dst[idx] = W[d * 64 + c];
    }
}

// ---------------- pack MLP weights into MFMA B-fragment order (bf16) ----------------
// B-frag for 16x16x32: lane l, elem j -> W[k = ks*32 + (l>>4)*8 + j][o = ot*16 + (l&15)]
// chunk = 512 u16 (64 lanes x 8), stored [chunk][lane][j]
// P1 @0: 4 chunks (ot=0..3, ks=0)      -> 2048
// P2 @2048: 16 chunks (ot*2+ks)        -> 8192
// P3 @10240: 48 chunks (ot*4+ks)       -> 24576
__global__ void k_pack(const float* __restrict__ Ws0, const float* __restrict__ Ws1,
                       const float* __restrict__ Ws2, unsigned short* __restrict__ PK) {
    int idx = blockIdx.x * 256 + threadIdx.x;
    if (idx >= 34816) return;
    if (idx < 2048) {
        int ot = idx >> 9, r = idx & 511, lane = r >> 3, j = r & 7;
        int k = (lane >> 4) * 8 + j, o = ot * 16 + (lane & 15);
        PK[idx] = f2bf(Ws0[o * 32 + k]);
    } else if (idx < 10240) {
        int i = idx - 2048, ch = i >> 9, r = i & 511, lane = r >> 3, j = r & 7;
        int ot = ch >> 1, ks = ch & 1;
        int k = ks * 32 + (lane >> 4) * 8 + j, o = ot * 16 + (lane & 15);
        PK[idx] = f2bf(Ws1[o * 64 + k]);
    } else {
        int i = idx - 10240, ch = i >> 9, r = i & 511, lane = r >> 3, j = r & 7;
        int ot = ch >> 2, ks = ch & 3;
        int k = ks * 32 + (lane >> 4) * 8 + j, o = ot * 16 + (lane & 15);
        PK[idx] = f2bf(Ws2[o * 128 + k]);
    }
}

// ---------------- node prep: normalize, decompose, channel-linear ----------------
__global__ __launch_bounds__(64) void k_nodeprep(const float* __restrict__ X,
                                                 const float* __restrict__ WtT,
                                                 float* __restrict__ Xn,
                                                 float* __restrict__ IAS) {
    int n = blockIdx.x, c = threadIdx.x;
    __shared__ float L[64][10];
    const float* xp = X + (size_t)n * 576 + c * 9;
    float x[9];
#pragma unroll
    for (int i = 0; i < 9; i++) x[i] = xp[i];
    float nrm = 0.f;
#pragma unroll
    for (int i = 0; i < 9; i++) nrm += x[i] * x[i];
    float inv = 1.0f / (nrm + 1.0f);
#pragma unroll
    for (int i = 0; i < 9; i++) x[i] *= inv;
    float* xnp = Xn + (size_t)n * 576 + c * 9;
#pragma unroll
    for (int i = 0; i < 9; i++) xnp[i] = x[i];
    float tr3 = (x[0] + x[4] + x[8]) * (1.0f / 3.0f);
    L[c][0] = tr3;
    L[c][1] = 0.5f * (x[1] - x[3]);
    L[c][2] = 0.5f * (x[2] - x[6]);
    L[c][3] = 0.5f * (x[5] - x[7]);
    L[c][4] = x[0] - tr3;
    L[c][5] = x[4] - tr3;
    L[c][6] = 0.5f * (x[1] + x[3]);
    L[c][7] = 0.5f * (x[2] + x[6]);
    L[c][8] = 0.5f * (x[5] + x[7]);
    __syncthreads();
    int d = c;
    const float* W0 = WtT;
    const float* W1 = WtT + 4096;
    const float* W2 = WtT + 8192;
    float aI = 0, aA0 = 0, aA1 = 0, aA2 = 0, aS0 = 0, aS1 = 0, aS2 = 0, aS3 = 0, aS4 = 0;
    for (int cc = 0; cc < 64; ++cc) {
        float w0 = W0[cc * 64 + d], w1 = W1[cc * 64 + d], w2 = W2[cc * 64 + d];
        aI  += w0 * L[cc][0];
        aA0 += w1 * L[cc][1]; aA1 += w1 * L[cc][2]; aA2 += w1 * L[cc][3];
        aS0 += w2 * L[cc][4]; aS1 += w2 * L[cc][5]; aS2 += w2 * L[cc][6];
        aS3 += w2 * L[cc][7]; aS4 += w2 * L[cc][8];
    }
    float* op = IAS + (size_t)n * 576;
    op[0 * 64 + d] = aI;
    op[1 * 64 + d] = aA0; op[2 * 64 + d] = aA1; op[3 * 64 + d] = aA2;
    op[4 * 64 + d] = aS0; op[5 * 64 + d] = aS1; op[6 * 64 + d] = aS2;
    op[7 * 64 + d] = aS3; op[8 * 64 + d] = aS4;
}

// ---------------- edge MLP via MFMA (64 edges/block, 4 waves, fused 3 layers) ----------------
__global__ __launch_bounds__(256) void k_mlp_mfma(const float* __restrict__ attr,
                                                  const float* __restrict__ ew,
                                                  const unsigned short* __restrict__ PK,
                                                  const float* __restrict__ bs0,
                                                  const float* __restrict__ bs1,
                                                  const float* __restrict__ bs2,
                                                  float* __restrict__ ea) {
    // padded strides (u16): 40, 72, 136 -> 2-way-or-less bank aliasing on b128 reads
    __shared__ unsigned short A1[64][40];
    __shared__ unsigned short H1[64][72];
    __shared__ unsigned short H2[64][136];
    __shared__ float Cs[64];
    int t = threadIdx.x;
    int e0 = blockIdx.x * 64;
    // stage attr -> bf16 LDS
    {
        int e = t >> 2, kq = (t & 3) * 8;
        const float* src = attr + (size_t)(e0 + e) * 32 + kq;
        float4 v0 = *(const float4*)src;
        float4 v1 = *(const float4*)(src + 4);
        bf16x8 pk;
        pk[0] = (short)f2bf(v0.x); pk[1] = (short)f2bf(v0.y);
        pk[2] = (short)f2bf(v0.z); pk[3] = (short)f2bf(v0.w);
        pk[4] = (short)f2bf(v1.x); pk[5] = (short)f2bf(v1.y);
        pk[6] = (short)f2bf(v1.z); pk[7] = (short)f2bf(v1.w);
        *(bf16x8*)&A1[e][kq] = pk;
    }
    if (t < 64) {
        float r = ew[e0 + t];
        Cs[t] = (r < 1.0f) ? 0.5f * (cosf(3.14159265358979f * r) + 1.0f) : 0.0f;
    }
    __syncthreads();
    int l = t & 63, w = t >> 6;
    int rb = w * 16;           // this wave's 16-edge row tile in LDS
    int lr = l & 15, lg = l >> 4;
    const unsigned short* P1 = PK;
    const unsigned short* P2 = PK + 2048;
    const unsigned short* P3 = PK + 10240;

    // ---- layer 1: 32 -> 64 ----
    bf16x8 a1 = *(const bf16x8*)&A1[rb + lr][lg * 8];
#pragma unroll
    for (int ot = 0; ot < 4; ++ot) {
        bf16x8 b = *(const bf16x8*)&P1[(ot * 64 + l) * 8];
        f32x4 acc = {0.f, 0.f, 0.f, 0.f};
        acc = __builtin_amdgcn_mfma_f32_16x16x32_bf16(a1, b, acc, 0, 0, 0);
        float bias = bs0[ot * 16 + lr];
#pragma unroll
        for (int r = 0; r < 4; ++r) {
            float v = silu_f(acc[r] + bias);
            H1[rb + lg * 4 + r][ot * 16 + lr] = f2bf(v);
        }
    }
    __syncthreads();

    // ---- layer 2: 64 -> 128 ----
    bf16x8 a2a = *(const bf16x8*)&H1[rb + lr][lg * 8];
    bf16x8 a2b = *(const bf16x8*)&H1[rb + lr][32 + lg * 8];
#pragma unroll
    for (int ot = 0; ot < 8; ++ot) {
        bf16x8 b0 = *(const bf16x8*)&P2[((ot * 2 + 0) * 64 + l) * 8];
        bf16x8 b1 = *(const bf16x8*)&P2[((ot * 2 + 1) * 64 + l) * 8];
        f32x4 acc = {0.f, 0.f, 0.f, 0.f};
        acc = __builtin_amdgcn_mfma_f32_16x16x32_bf16(a2a, b0, acc, 0, 0, 0);
        acc = __builtin_amdgcn_mfma_f32_16x16x32_bf16(a2b, b1, acc, 0, 0, 0);
        float bias = bs1[ot * 16 + lr];
#pragma unroll
        for (int r = 0; r < 4; ++r) {
            float v = silu_f(acc[r] + bias);
            H2[rb + lg * 4 + r][ot * 16 + lr] = f2bf(v);
        }
    }
    __syncthreads();

    // ---- layer 3: 128 -> 192, scale by C, write ----
    bf16x8 a3[4];
#pragma unroll
    for (int ks = 0; ks < 4; ++ks)
        a3[ks] = *(const bf16x8*)&H2[rb + lr][ks * 32 + lg * 8];
    float Cr[4];
#pragma unroll
    for (int r = 0; r < 4; ++r) Cr[r] = Cs[rb + lg * 4 + r];
#pragma unroll
    for (int ot = 0; ot < 12; ++ot) {
        f32x4 acc = {0.f, 0.f, 0.f, 0.f};
#pragma unroll
        for (int ks = 0; ks < 4; ++ks) {
            bf16x8 b = *(const bf16x8*)&P3[((ot * 4 + ks) * 64 + l) * 8];
            acc = __builtin_amdgcn_mfma_f32_16x16x32_bf16(a3[ks], b, acc, 0, 0, 0);
        }
        float bias = bs2[ot * 16 + lr];
#pragma unroll
        for (int r = 0; r < 4; ++r) {
            float v = silu_f(acc[r] + bias) * Cr[r];
            ea[(size_t)(e0 + rb + lg * 4 + r) * 192 + ot * 16 + lr] = v;
        }
    }
}

// ---------------- CSR build ----------------
__global__ void k_count(const int* __restrict__ ei, int* __restrict__ counts) {
    int e = blockIdx.x * 256 + threadIdx.x;
    if (e < EE) atomicAdd(&counts[ei[e]], 1);
}

__global__ __launch_bounds__(256) void k_scan(const int* __restrict__ counts,
                                              int* __restrict__ offsets) {
    __shared__ int sums[256];
    int t = threadIdx.x;
    const int CH = 40;
    int base = t * CH;
    int s = 0;
    for (int i = 0; i < CH; i++) {
        int idx = base + i;
        if (idx < NN) s += counts[idx];
    }
    sums[t] = s;
    __syncthreads();
    for (int off = 1; off < 256; off <<= 1) {
        int tmp = (t >= off) ? sums[t - off] : 0;
        __syncthreads();
        sums[t] += tmp;
        __syncthreads();
    }
    int run = sums[t] - s;
    for (int i = 0; i < CH; i++) {
        int idx = base + i;
        if (idx < NN) { offsets[idx] = run; run += counts[idx]; }
    }
    if (t == 255) offsets[NN] = run;
}

__global__ void k_fill(const int* __restrict__ ei, const int* __restrict__ offsets,
                       int* __restrict__ cursor, int* __restrict__ bucket) {
    int e = blockIdx.x * 256 + threadIdx.x;
    if (e < EE) {
        int s = ei[e];
        int pos = offsets[s] + atomicAdd(&cursor[s], 1);
        bucket[pos] = e;
    }
}

// ---------------- message aggregation (1 wave / node) ----------------
__global__ __launch_bounds__(64) void k_agg(const int* __restrict__ ei,
                                            const int* __restrict__ offsets,
                                            const int* __restrict__ bucket,
                                            const float* __restrict__ ea,
                                            const float* __restrict__ IAS,
                                            float* __restrict__ Msg) {
    int n = blockIdx.x, c = threadIdx.x;
    int beg = offsets[n], end = offsets[n + 1];
    float mI = 0, mA0 = 0, mA1 = 0, mA2 = 0, mS0 = 0, mS1 = 0, mS2 = 0, mS3 = 0, mS4 = 0;
    for (int i = beg; i < end; ++i) {
        int eid = bucket[i];
        int dst = ei[EE + eid];
        const float* eap = ea + (size_t)eid * 192 + 3 * c;
        float e0 = eap[0], e1 = eap[1], e2 = eap[2];
        const float* ip = IAS + (size_t)dst * 576;
        mI  += e0 * ip[c];
        mA0 += e1 * ip[64 + c];  mA1 += e1 * ip[128 + c]; mA2 += e1 * ip[192 + c];
        mS0 += e2 * ip[256 + c]; mS1 += e2 * ip[320 + c]; mS2 += e2 * ip[384 + c];
        mS3 += e2 * ip[448 + c]; mS4 += e2 * ip[512 + c];
    }
    float* mp = Msg + (size_t)n * 576;
    mp[c] = mI;
    mp[64 + c] = mA0;  mp[128 + c] = mA1; mp[192 + c] = mA2;
    mp[256 + c] = mS0; mp[320 + c] = mS1; mp[384 + c] = mS2;
    mp[448 + c] = mS3; mp[512 + c] = mS4;
}

// ---------------- output stage ----------------
__global__ __launch_bounds__(64) void k_out(const float* __restrict__ Msg,
                                            const float* __restrict__ IAS,
                                            const float* __restrict__ Xn,
                                            const float* __restrict__ WtT,
                                            float* __restrict__ out) {
    int n = blockIdx.x, c = threadIdx.x;
    __shared__ float L[64][10];
    const float* mp = Msg + (size_t)n * 576;
    const float* ip = IAS + (size_t)n * 576;
    float mI = mp[c], mA0 = mp[64 + c], mA1 = mp[128 + c], mA2 = mp[192 + c];
    float mS0 = mp[256 + c], mS1 = mp[320 + c], mS2 = mp[384 + c], mS3 = mp[448 + c], mS4 = mp[512 + c];
    float yI = ip[c], yA0 = ip[64 + c], yA1 = ip[128 + c], yA2 = ip[192 + c];
    float yS0 = ip[256 + c], yS1 = ip[320 + c], yS2 = ip[384 + c], yS3 = ip[448 + c], yS4 = ip[512 + c];
    float M[3][3] = {
        { mI + mS0,   mA0 + mS2,  mA1 + mS3 },
        { -mA0 + mS2, mI + mS1,   mA2 + mS4 },
        { -mA1 + mS3, -mA2 + mS4, mI - mS0 - mS1 } };
    float Y[3][3] = {
        { yI + yS0,   yA0 + yS2,  yA1 + yS3 },
        { -yA0 + yS2, yI + yS1,   yA2 + yS4 },
        { -yA1 + yS3, -yA2 + yS4, yI - yS0 - yS1 } };
    float AB[3][3];
#pragma unroll
    for (int i = 0; i < 3; i++)
#pragma unroll
        for (int j = 0; j < 3; j++) {
            float s = 0.f;
#pragma unroll
            for (int k = 0; k < 3; k++) s += M[i][k] * Y[k][j] + Y[i][k] * M[k][j];
            AB[i][j] = s;
        }
    float tr3 = (AB[0][0] + AB[1][1] + AB[2][2]) * (1.0f / 3.0f);
    float fro = 0.f;
#pragma unroll
    for (int i = 0; i < 3; i++)
#pragma unroll
        for (int j = 0; j < 3; j++) fro += AB[i][j] * AB[i][j];
    float inv = 1.0f / (fro + 1.0f);
    L[c][0] = tr3 * inv;
    L[c][1] = 0.5f * (AB[0][1] - AB[1][0]) * inv;
    L[c][2] = 0.5f * (AB[0][2] - AB[2][0]) * inv;
    L[c][3] = 0.5f * (AB[1][2] - AB[2][1]) * inv;
    L[c][4] = (AB[0][0] - tr3) * inv;
    L[c][5] = (AB[1][1] - tr3) * inv;
    L[c][6] = 0.5f * (AB[0][1] + AB[1][0]) * inv;
    L[c][7] = 0.5f * (AB[0][2] + AB[2][0]) * inv;
    L[c][8] = 0.5f * (AB[1][2] + AB[2][1]) * inv;
    __syncthreads();
    int d = c;
    const float* W3 = WtT + 3 * 4096;
    const float* W4 = WtT + 4 * 4096;
    const float* W5 = WtT + 5 * 4096;
    float aI = 0, aA0 = 0, aA1 = 0, aA2 = 0, aS0 = 0, aS1 = 0, aS2 = 0, aS3 = 0, aS4 = 0;
    for (int cc = 0; cc < 64; ++cc) {
        float w3 = W3[cc * 64 + d], w4 = W4[cc * 64 + d], w5 = W5[cc * 64 + d];
        aI  += w3 * L[cc][0];
        aA0 += w4 * L[cc][1]; aA1 += w4 * L[cc][2]; aA2 += w4 * L[cc][3];
        aS0 += w5 * L[cc][4]; aS1 += w5 * L[cc][5]; aS2 += w5 * L[cc][6];
        aS3 += w5 * L[cc][7]; aS4 += w5 * L[cc][8];
    }
    float dX[3][3] = {
        { aI + aS0,   aA0 + aS2,  aA1 + aS3 },
        { -aA0 + aS2, aI + aS1,   aA2 + aS4 },
        { -aA1 + aS3, -aA2 + aS4, aI - aS0 - aS1 } };
    float D2[3][3];
#pragma unroll
    for (int i = 0; i < 3; i++)
#pragma unroll
        for (int j = 0; j < 3; j++) {
            float s = 0.f;
#pragma unroll
            for (int k = 0; k < 3; k++) s += dX[i][k] * dX[k][j];
            D2[i][j] = s;
        }
    const float* xp = Xn + (size_t)n * 576 + d * 9;
    float* op = out + (size_t)n * 576 + d * 9;
#pragma unroll
    for (int i = 0; i < 3; i++)
#pragma unroll
        for (int j = 0; j < 3; j++) op[i * 3 + j] = xp[i * 3 + j] + dX[i][j] + D2[i][j];
}

extern "C" void kernel_launch(void* const* d_in, const int* in_sizes, int n_in,
                              void* d_out, int out_size, void* d_ws, size_t ws_size,
                              hipStream_t stream) {
    (void)in_sizes; (void)n_in; (void)out_size; (void)ws_size;
    const int* ei = (const int*)d_in[0];
    const float* ew = (const float*)d_in[1];
    const float* attr = (const float*)d_in[2];
    const float* X = (const float*)d_in[3];
    const float* Ws0 = (const float*)d_in[4];
    const float* bs0 = (const float*)d_in[5];
    const float* Ws1 = (const float*)d_in[6];
    const float* bs1 = (const float*)d_in[7];
    const float* Ws2 = (const float*)d_in[8];
    const float* bs2 = (const float*)d_in[9];
    const float* Wt0 = (const float*)d_in[10];
    const float* Wt1 = (const float*)d_in[11];
    const float* Wt2 = (const float*)d_in[12];
    const float* Wt3 = (const float*)d_in[13];
    const float* Wt4 = (const float*)d_in[14];
    const float* Wt5 = (const float*)d_in[15];
    float* ws = (float*)d_ws;
    int* ibase = (int*)(ws + OFF_INT);
    int* counts = ibase;
    int* cursor = ibase + NN;
    int* offsets = ibase + 2 * NN;
    int* bucket = ibase + 3 * NN + 1;

    hipMemsetAsync(counts, 0, 2 * NN * sizeof(int), stream);
    k_transpose<<<96, 256, 0, stream>>>(Wt0, Wt1, Wt2, Wt3, Wt4, Wt5, ws);
    k_pack<<<136, 256, 0, stream>>>(Ws0, Ws1, Ws2, (unsigned short*)(ws + OFF_PK));
    k_nodeprep<<<NN, 64, 0, stream>>>(X, ws, ws + OFF_XN, ws + OFF_IAS);
    k_mlp_mfma<<<EE / 64, 256, 0, stream>>>(attr, ew, (const unsigned short*)(ws + OFF_PK),
                                            bs0, bs1, bs2, ws + OFF_EA);
    k_count<<<(EE + 255) / 256, 256, 0, stream>>>(ei, counts);
    k_scan<<<1, 256, 0, stream>>>(counts, offsets);
    k_fill<<<(EE + 255) / 256, 256, 0, stream>>>(ei, offsets, cursor, bucket);
    k_agg<<<NN, 64, 0, stream>>>(ei, offsets, bucket, ws + OFF_EA, ws + OFF_IAS, ws + OFF_MSG);
    k_out<<<NN, 64, 0, stream>>>(ws + OFF_MSG, ws + OFF_IAS, ws + OFF_XN, ws, (float*)d_out);
}

// Round 3
// 201.617 us; speedup vs baseline: 5.3578x; 1.1786x over previous
//
#include <hip/hip_runtime.h>
#include <hip/hip_fp16.h>
#include <math.h>

#define NN 10000
#define EE 160000

// ---- workspace layout (float indices) ----
#define OFF_WTT 0               // [6][64][64] f32                       len 24576
#define OFF_PK  24576           // packed bf16 MLP weights, 34816 u16    len 17408
#define OFF_XN  41984           // [N][64][9] f32                        len 5760000
#define OFF_IAS 5801984         // [N][9][64] f32                        len 5760000
#define OFF_MSG 11561984        // [N][9][64] f32                        len 5760000
#define OFF_IASH 17321984       // [N][9][64] fp16 (5760000 u16)         len 2880000
#define OFF_EAH 20201984        // [E][192] fp16 (30720000 u16)          len 15360000
#define OFF_INT 35561984        // counts[N] cursor[N] offsets[N+1] bucket[E] dstp[E]

typedef __attribute__((ext_vector_type(8))) short bf16x8;
typedef __attribute__((ext_vector_type(4))) float f32x4;

__device__ __forceinline__ float silu_f(float x) { return x / (1.0f + __expf(-x)); }

__device__ __forceinline__ unsigned short f2bf(float f) {
    unsigned int u = __float_as_uint(f);
    unsigned int r = (u + 0x7FFFu + ((u >> 16) & 1u)) >> 16;
    return (unsigned short)r;
}
__device__ __forceinline__ unsigned short f2h(float f) {
    __half h = __float2half(f);
    return *(unsigned short*)&h;
}
__device__ __forceinline__ float h2f(unsigned short u) {
    __half h = *(__half*)&u;
    return __half2float(h);
}

// ---------------- weight transpose (node-side Wt only) ----------------
__global__ void k_transpose(const float* __restrict__ Wt0, const float* __restrict__ Wt1,
                            const float* __restrict__ Wt2, const float* __restrict__ Wt3,
                            const float* __restrict__ Wt4, const float* __restrict__ Wt5,
                            float* __restrict__ dst) {
    int idx = blockIdx.x * 256 + threadIdx.x;
    if (idx < 24576) {
        int k = idx >> 12, r = idx & 4095;
        int c = r >> 6, d = r & 63;
        const float* W = (k == 0) ? Wt0 : (k == 1) ? Wt1 : (k == 2) ? Wt2
                       : (k == 3) ? Wt3 : (k == 4) ? Wt4 : Wt5;
        dst[idx] = W[d * 64 + c];
    }
}

// ---------------- pack MLP weights into MFMA B-fragment order (bf16) ----------------
__global__ void k_pack(const float* __restrict__ Ws0, const float* __restrict__ Ws1,
                       const float* __restrict__ Ws2, unsigned short* __restrict__ PK) {
    int idx = blockIdx.x * 256 + threadIdx.x;
    if (idx >= 34816) return;
    if (idx < 2048) {
        int ot = idx >> 9, r = idx & 511, lane = r >> 3, j = r & 7;
        int k = (lane >> 4) * 8 + j, o = ot * 16 + (lane & 15);
        PK[idx] = f2bf(Ws0[o * 32 + k]);
    } else if (idx < 10240) {
        int i = idx - 2048, ch = i >> 9, r = i & 511, lane = r >> 3, j = r & 7;
        int ot = ch >> 1, ks = ch & 1;
        int k = ks * 32 + (lane >> 4) * 8 + j, o = ot * 16 + (lane & 15);
        PK[idx] = f2bf(Ws1[o * 64 + k]);
    } else {
        int i = idx - 10240, ch = i >> 9, r = i & 511, lane = r >> 3, j = r & 7;
        int ot = ch >> 2, ks = ch & 3;
        int k = ks * 32 + (lane >> 4) * 8 + j, o = ot * 16 + (lane & 15);
        PK[idx] = f2bf(Ws2[o * 128 + k]);
    }
}

// ---------------- node prep ----------------
__global__ __launch_bounds__(64) void k_nodeprep(const float* __restrict__ X,
                                                 const float* __restrict__ WtT,
                                                 float* __restrict__ Xn,
                                                 float* __restrict__ IAS,
                                                 unsigned short* __restrict__ IASh) {
    int n = blockIdx.x, c = threadIdx.x;
    __shared__ float L[64][10];
    const float* xp = X + (size_t)n * 576 + c * 9;
    float x[9];
#pragma unroll
    for (int i = 0; i < 9; i++) x[i] = xp[i];
    float nrm = 0.f;
#pragma unroll
    for (int i = 0; i < 9; i++) nrm += x[i] * x[i];
    float inv = 1.0f / (nrm + 1.0f);
#pragma unroll
    for (int i = 0; i < 9; i++) x[i] *= inv;
    float* xnp = Xn + (size_t)n * 576 + c * 9;
#pragma unroll
    for (int i = 0; i < 9; i++) xnp[i] = x[i];
    float tr3 = (x[0] + x[4] + x[8]) * (1.0f / 3.0f);
    L[c][0] = tr3;
    L[c][1] = 0.5f * (x[1] - x[3]);
    L[c][2] = 0.5f * (x[2] - x[6]);
    L[c][3] = 0.5f * (x[5] - x[7]);
    L[c][4] = x[0] - tr3;
    L[c][5] = x[4] - tr3;
    L[c][6] = 0.5f * (x[1] + x[3]);
    L[c][7] = 0.5f * (x[2] + x[6]);
    L[c][8] = 0.5f * (x[5] + x[7]);
    __syncthreads();
    int d = c;
    const float* W0 = WtT;
    const float* W1 = WtT + 4096;
    const float* W2 = WtT + 8192;
    float aI = 0, aA0 = 0, aA1 = 0, aA2 = 0, aS0 = 0, aS1 = 0, aS2 = 0, aS3 = 0, aS4 = 0;
    for (int cc = 0; cc < 64; ++cc) {
        float w0 = W0[cc * 64 + d], w1 = W1[cc * 64 + d], w2 = W2[cc * 64 + d];
        aI  += w0 * L[cc][0];
        aA0 += w1 * L[cc][1]; aA1 += w1 * L[cc][2]; aA2 += w1 * L[cc][3];
        aS0 += w2 * L[cc][4]; aS1 += w2 * L[cc][5]; aS2 += w2 * L[cc][6];
        aS3 += w2 * L[cc][7]; aS4 += w2 * L[cc][8];
    }
    float* op = IAS + (size_t)n * 576;
    unsigned short* oh = IASh + (size_t)n * 576;
    float v[9] = {aI, aA0, aA1, aA2, aS0, aS1, aS2, aS3, aS4};
#pragma unroll
    for (int i = 0; i < 9; i++) {
        op[i * 64 + d] = v[i];
        oh[i * 64 + d] = f2h(v[i]);
    }
}

// ---------------- CSR build ----------------
__global__ void k_count(const int* __restrict__ ei, int* __restrict__ counts) {
    int e = blockIdx.x * 256 + threadIdx.x;
    if (e < EE) atomicAdd(&counts[ei[e]], 1);
}

__global__ __launch_bounds__(256) void k_scan(const int* __restrict__ counts,
                                              int* __restrict__ offsets) {
    __shared__ int sums[256];
    int t = threadIdx.x;
    const int CH = 40;
    int base = t * CH;
    int s = 0;
    for (int i = 0; i < CH; i++) {
        int idx = base + i;
        if (idx < NN) s += counts[idx];
    }
    sums[t] = s;
    __syncthreads();
    for (int off = 1; off < 256; off <<= 1) {
        int tmp = (t >= off) ? sums[t - off] : 0;
        __syncthreads();
        sums[t] += tmp;
        __syncthreads();
    }
    int run = sums[t] - s;
    for (int i = 0; i < CH; i++) {
        int idx = base + i;
        if (idx < NN) { offsets[idx] = run; run += counts[idx]; }
    }
    if (t == 255) offsets[NN] = run;
}

__global__ void k_fill(const int* __restrict__ ei, const int* __restrict__ offsets,
                       int* __restrict__ cursor, int* __restrict__ bucket,
                       int* __restrict__ dstp) {
    int e = blockIdx.x * 256 + threadIdx.x;
    if (e < EE) {
        int s = ei[e];
        int pos = offsets[s] + atomicAdd(&cursor[s], 1);
        bucket[pos] = e;
        dstp[pos] = ei[EE + e];
    }
}

// ---------------- edge MLP via MFMA, bucket-ordered, fp16 output ----------------
__global__ __launch_bounds__(256) void k_mlp_mfma(const float* __restrict__ attr,
                                                  const float* __restrict__ ew,
                                                  const int* __restrict__ bucket,
                                                  const unsigned short* __restrict__ PK,
                                                  const float* __restrict__ bs0,
                                                  const float* __restrict__ bs1,
                                                  const float* __restrict__ bs2,
                                                  unsigned short* __restrict__ eah) {
    __shared__ unsigned short A1[64][40];
    __shared__ unsigned short H1[64][72];
    __shared__ unsigned short H2[64][136];
    __shared__ float Cs[64];
    int t = threadIdx.x;
    int e0 = blockIdx.x * 64;
    {
        int e = t >> 2, kq = (t & 3) * 8;
        int eid = bucket[e0 + e];
        const float* src = attr + (size_t)eid * 32 + kq;
        float4 v0 = *(const float4*)src;
        float4 v1 = *(const float4*)(src + 4);
        bf16x8 pk;
        pk[0] = (short)f2bf(v0.x); pk[1] = (short)f2bf(v0.y);
        pk[2] = (short)f2bf(v0.z); pk[3] = (short)f2bf(v0.w);
        pk[4] = (short)f2bf(v1.x); pk[5] = (short)f2bf(v1.y);
        pk[6] = (short)f2bf(v1.z); pk[7] = (short)f2bf(v1.w);
        *(bf16x8*)&A1[e][kq] = pk;
    }
    if (t < 64) {
        int eid = bucket[e0 + t];
        float r = ew[eid];
        Cs[t] = (r < 1.0f) ? 0.5f * (cosf(3.14159265358979f * r) + 1.0f) : 0.0f;
    }
    __syncthreads();
    int l = t & 63, w = t >> 6;
    int rb = w * 16;
    int lr = l & 15, lg = l >> 4;
    const unsigned short* P1 = PK;
    const unsigned short* P2 = PK + 2048;
    const unsigned short* P3 = PK + 10240;

    // ---- layer 1: 32 -> 64 ----
    bf16x8 a1 = *(const bf16x8*)&A1[rb + lr][lg * 8];
#pragma unroll
    for (int ot = 0; ot < 4; ++ot) {
        bf16x8 b = *(const bf16x8*)&P1[(ot * 64 + l) * 8];
        f32x4 acc = {0.f, 0.f, 0.f, 0.f};
        acc = __builtin_amdgcn_mfma_f32_16x16x32_bf16(a1, b, acc, 0, 0, 0);
        float bias = bs0[ot * 16 + lr];
#pragma unroll
        for (int r = 0; r < 4; ++r) {
            float v = silu_f(acc[r] + bias);
            H1[rb + lg * 4 + r][ot * 16 + lr] = f2bf(v);
        }
    }
    __syncthreads();

    // ---- layer 2: 64 -> 128 ----
    bf16x8 a2a = *(const bf16x8*)&H1[rb + lr][lg * 8];
    bf16x8 a2b = *(const bf16x8*)&H1[rb + lr][32 + lg * 8];
#pragma unroll
    for (int ot = 0; ot < 8; ++ot) {
        bf16x8 b0 = *(const bf16x8*)&P2[((ot * 2 + 0) * 64 + l) * 8];
        bf16x8 b1 = *(const bf16x8*)&P2[((ot * 2 + 1) * 64 + l) * 8];
        f32x4 acc = {0.f, 0.f, 0.f, 0.f};
        acc = __builtin_amdgcn_mfma_f32_16x16x32_bf16(a2a, b0, acc, 0, 0, 0);
        acc = __builtin_amdgcn_mfma_f32_16x16x32_bf16(a2b, b1, acc, 0, 0, 0);
        float bias = bs1[ot * 16 + lr];
#pragma unroll
        for (int r = 0; r < 4; ++r) {
            float v = silu_f(acc[r] + bias);
            H2[rb + lg * 4 + r][ot * 16 + lr] = f2bf(v);
        }
    }
    __syncthreads();

    // ---- layer 3: 128 -> 192, scale by C, write fp16 ----
    bf16x8 a3[4];
#pragma unroll
    for (int ks = 0; ks < 4; ++ks)
        a3[ks] = *(const bf16x8*)&H2[rb + lr][ks * 32 + lg * 8];
    float Cr[4];
#pragma unroll
    for (int r = 0; r < 4; ++r) Cr[r] = Cs[rb + lg * 4 + r];
#pragma unroll
    for (int ot = 0; ot < 12; ++ot) {
        f32x4 acc = {0.f, 0.f, 0.f, 0.f};
#pragma unroll
        for (int ks = 0; ks < 4; ++ks) {
            bf16x8 b = *(const bf16x8*)&P3[((ot * 4 + ks) * 64 + l) * 8];
            acc = __builtin_amdgcn_mfma_f32_16x16x32_bf16(a3[ks], b, acc, 0, 0, 0);
        }
        float bias = bs2[ot * 16 + lr];
#pragma unroll
        for (int r = 0; r < 4; ++r) {
            float v = silu_f(acc[r] + bias) * Cr[r];
            eah[(size_t)(e0 + rb + lg * 4 + r) * 192 + ot * 16 + lr] = f2h(v);
        }
    }
}

// ---------------- message aggregation (1 wave / node, fp16 streams) ----------------
__global__ __launch_bounds__(64) void k_agg(const int* __restrict__ offsets,
                                            const int* __restrict__ dstp,
                                            const unsigned short* __restrict__ eah,
                                            const unsigned short* __restrict__ IASh,
                                            float* __restrict__ Msg) {
    int n = blockIdx.x, c = threadIdx.x;
    int beg = offsets[n], end = offsets[n + 1];
    float mI = 0, mA0 = 0, mA1 = 0, mA2 = 0, mS0 = 0, mS1 = 0, mS2 = 0, mS3 = 0, mS4 = 0;
    for (int i = beg; i < end; ++i) {
        int dst = dstp[i];
        const unsigned short* ep = eah + (size_t)i * 192 + 3 * c;
        float e0 = h2f(ep[0]), e1 = h2f(ep[1]), e2 = h2f(ep[2]);
        const unsigned short* ip = IASh + (size_t)dst * 576;
        mI  += e0 * h2f(ip[c]);
        mA0 += e1 * h2f(ip[64 + c]);  mA1 += e1 * h2f(ip[128 + c]); mA2 += e1 * h2f(ip[192 + c]);
        mS0 += e2 * h2f(ip[256 + c]); mS1 += e2 * h2f(ip[320 + c]); mS2 += e2 * h2f(ip[384 + c]);
        mS3 += e2 * h2f(ip[448 + c]); mS4 += e2 * h2f(ip[512 + c]);
    }
    float* mp = Msg + (size_t)n * 576;
    mp[c] = mI;
    mp[64 + c] = mA0;  mp[128 + c] = mA1; mp[192 + c] = mA2;
    mp[256 + c] = mS0; mp[320 + c] = mS1; mp[384 + c] = mS2;
    mp[448 + c] = mS3; mp[512 + c] = mS4;
}

// ---------------- output stage ----------------
__global__ __launch_bounds__(64) void k_out(const float* __restrict__ Msg,
                                            const float* __restrict__ IAS,
                                            const float* __restrict__ Xn,
                                            const float* __restrict__ WtT,
                                            float* __restrict__ out) {
    int n = blockIdx.x, c = threadIdx.x;
    __shared__ float L[64][10];
    const float* mp = Msg + (size_t)n * 576;
    const float* ip = IAS + (size_t)n * 576;
    float mI = mp[c], mA0 = mp[64 + c], mA1 = mp[128 + c], mA2 = mp[192 + c];
    float mS0 = mp[256 + c], mS1 = mp[320 + c], mS2 = mp[384 + c], mS3 = mp[448 + c], mS4 = mp[512 + c];
    float yI = ip[c], yA0 = ip[64 + c], yA1 = ip[128 + c], yA2 = ip[192 + c];
    float yS0 = ip[256 + c], yS1 = ip[320 + c], yS2 = ip[384 + c], yS3 = ip[448 + c], yS4 = ip[512 + c];
    float M[3][3] = {
        { mI + mS0,   mA0 + mS2,  mA1 + mS3 },
        { -mA0 + mS2, mI + mS1,   mA2 + mS4 },
        { -mA1 + mS3, -mA2 + mS4, mI - mS0 - mS1 } };
    float Y[3][3] = {
        { yI + yS0,   yA0 + yS2,  yA1 + yS3 },
        { -yA0 + yS2, yI + yS1,   yA2 + yS4 },
        { -yA1 + yS3, -yA2 + yS4, yI - yS0 - yS1 } };
    float AB[3][3];
#pragma unroll
    for (int i = 0; i < 3; i++)
#pragma unroll
        for (int j = 0; j < 3; j++) {
            float s = 0.f;
#pragma unroll
            for (int k = 0; k < 3; k++) s += M[i][k] * Y[k][j] + Y[i][k] * M[k][j];
            AB[i][j] = s;
        }
    float tr3 = (AB[0][0] + AB[1][1] + AB[2][2]) * (1.0f / 3.0f);
    float fro = 0.f;
#pragma unroll
    for (int i = 0; i < 3; i++)
#pragma unroll
        for (int j = 0; j < 3; j++) fro += AB[i][j] * AB[i][j];
    float inv = 1.0f / (fro + 1.0f);
    L[c][0] = tr3 * inv;
    L[c][1] = 0.5f * (AB[0][1] - AB[1][0]) * inv;
    L[c][2] = 0.5f * (AB[0][2] - AB[2][0]) * inv;
    L[c][3] = 0.5f * (AB[1][2] - AB[2][1]) * inv;
    L[c][4] = (AB[0][0] - tr3) * inv;
    L[c][5] = (AB[1][1] - tr3) * inv;
    L[c][6] = 0.5f * (AB[0][1] + AB[1][0]) * inv;
    L[c][7] = 0.5f * (AB[0][2] + AB[2][0]) * inv;
    L[c][8] = 0.5f * (AB[1][2] + AB[2][1]) * inv;
    __syncthreads();
    int d = c;
    const float* W3 = WtT + 3 * 4096;
    const float* W4 = WtT + 4 * 4096;
    const float* W5 = WtT + 5 * 4096;
    float aI = 0, aA0 = 0, aA1 = 0, aA2 = 0, aS0 = 0, aS1 = 0, aS2 = 0, aS3 = 0, aS4 = 0;
    for (int cc = 0; cc < 64; ++cc) {
        float w3 = W3[cc * 64 + d], w4 = W4[cc * 64 + d], w5 = W5[cc * 64 + d];
        aI  += w3 * L[cc][0];
        aA0 += w4 * L[cc][1]; aA1 += w4 * L[cc][2]; aA2 += w4 * L[cc][3];
        aS0 += w5 * L[cc][4]; aS1 += w5 * L[cc][5]; aS2 += w5 * L[cc][6];
        aS3 += w5 * L[cc][7]; aS4 += w5 * L[cc][8];
    }
    float dX[3][3] = {
        { aI + aS0,   aA0 + aS2,  aA1 + aS3 },
        { -aA0 + aS2, aI + aS1,   aA2 + aS4 },
        { -aA1 + aS3, -aA2 + aS4, aI - aS0 - aS1 } };
    float D2[3][3];
#pragma unroll
    for (int i = 0; i < 3; i++)
#pragma unroll
        for (int j = 0; j < 3; j++) {
            float s = 0.f;
#pragma unroll
            for (int k = 0; k < 3; k++) s += dX[i][k] * dX[k][j];
            D2[i][j] = s;
        }
    const float* xp = Xn + (size_t)n * 576 + d * 9;
    float* op = out + (size_t)n * 576 + d * 9;
#pragma unroll
    for (int i = 0; i < 3; i++)
#pragma unroll
        for (int j = 0; j < 3; j++) op[i * 3 + j] = xp[i * 3 + j] + dX[i][j] + D2[i][j];
}

extern "C" void kernel_launch(void* const* d_in, const int* in_sizes, int n_in,
                              void* d_out, int out_size, void* d_ws, size_t ws_size,
                              hipStream_t stream) {
    (void)in_sizes; (void)n_in; (void)out_size; (void)ws_size;
    const int* ei = (const int*)d_in[0];
    const float* ew = (const float*)d_in[1];
    const float* attr = (const float*)d_in[2];
    const float* X = (const float*)d_in[3];
    const float* Ws0 = (const float*)d_in[4];
    const float* bs0 = (const float*)d_in[5];
    const float* Ws1 = (const float*)d_in[6];
    const float* bs1 = (const float*)d_in[7];
    const float* Ws2 = (const float*)d_in[8];
    const float* bs2 = (const float*)d_in[9];
    const float* Wt0 = (const float*)d_in[10];
    const float* Wt1 = (const float*)d_in[11];
    const float* Wt2 = (const float*)d_in[12];
    const float* Wt3 = (const float*)d_in[13];
    const float* Wt4 = (const float*)d_in[14];
    const float* Wt5 = (const float*)d_in[15];
    float* ws = (float*)d_ws;
    int* ibase = (int*)(ws + OFF_INT);
    int* counts = ibase;
    int* cursor = ibase + NN;
    int* offsets = ibase + 2 * NN;
    int* bucket = ibase + 3 * NN + 1;
    int* dstp = bucket + EE;
    unsigned short* IASh = (unsigned short*)(ws + OFF_IASH);
    unsigned short* eah = (unsigned short*)(ws + OFF_EAH);

    hipMemsetAsync(counts, 0, 2 * NN * sizeof(int), stream);
    k_transpose<<<96, 256, 0, stream>>>(Wt0, Wt1, Wt2, Wt3, Wt4, Wt5, ws);
    k_pack<<<136, 256, 0, stream>>>(Ws0, Ws1, Ws2, (unsigned short*)(ws + OFF_PK));
    k_count<<<(EE + 255) / 256, 256, 0, stream>>>(ei, counts);
    k_scan<<<1, 256, 0, stream>>>(counts, offsets);
    k_fill<<<(EE + 255) / 256, 256, 0, stream>>>(ei, offsets, cursor, bucket, dstp);
    k_nodeprep<<<NN, 64, 0, stream>>>(X, ws, ws + OFF_XN, ws + OFF_IAS, IASh);
    k_mlp_mfma<<<EE / 64, 256, 0, stream>>>(attr, ew, bucket, (const unsigned short*)(ws + OFF_PK),
                                            bs0, bs1, bs2, eah);
    k_agg<<<NN, 64, 0, stream>>>(offsets, dstp, eah, IASh, ws + OFF_MSG);
    k_out<<<NN, 64, 0, stream>>>(ws + OFF_MSG, ws + OFF_IAS, ws + OFF_XN, ws, (float*)d_out);
}

// Round 5
// 185.710 us; speedup vs baseline: 5.8167x; 1.0857x over previous
//
#include <hip/hip_runtime.h>
#include <math.h>

#define NN 10000
#define EE 160000

// ---- workspace layout (float indices) ----
#define OFF_WTT 0            // [6][64][64] f32 (WtT[k][c][d] = Wt_k[d][c])   len 24576
#define OFF_PK  24576        // packed f16 MLP weights, 34816 u16             len 17408
#define OFF_B2P 41984        // permuted bs2 f32 [192]                        len 192
#define OFF_IASH 42176       // [N][64][12] u16 (9 comps + 3 pad)             len 3840000 f
#define OFF_EAH 3882176      // [E][192] f16, ch' = comp*64+unit              len 15360000 f
#define OFF_INT 19242176     // counts[N] cursor[N] offsets[N+1] bucket[E] dstp[E]

typedef __attribute__((ext_vector_type(8))) _Float16 h16x8;
typedef __attribute__((ext_vector_type(2))) __fp16 fp16x2_raw;
typedef __attribute__((ext_vector_type(4))) float f32x4;

__device__ __forceinline__ float silu_f(float x) {
    return x * __builtin_amdgcn_rcpf(1.0f + __expf(-x));
}
__device__ __forceinline__ unsigned int pkh(float a, float b) {
    union { fp16x2_raw h; unsigned int u; } cv;
    cv.h = __builtin_amdgcn_cvt_pkrtz(a, b);
    return cv.u;
}
__device__ __forceinline__ unsigned short f2h(float f) {
    union { _Float16 h; unsigned short u; } cv; cv.h = (_Float16)f; return cv.u;
}
__device__ __forceinline__ float h2f(unsigned short s) {
    union { unsigned short u; _Float16 h; } cv; cv.u = s; return (float)cv.h;
}
__device__ __forceinline__ float h2f_lo(unsigned int u) { return h2f((unsigned short)(u & 0xffffu)); }
__device__ __forceinline__ float h2f_hi(unsigned int u) { return h2f((unsigned short)(u >> 16)); }

// ---------------- prep: Wt transpose + f16 weight pack + bs2 permute + degree count ----------------
__global__ void k_prep(const float* __restrict__ Wt0, const float* __restrict__ Wt1,
                       const float* __restrict__ Wt2, const float* __restrict__ Wt3,
                       const float* __restrict__ Wt4, const float* __restrict__ Wt5,
                       const float* __restrict__ Ws0, const float* __restrict__ Ws1,
                       const float* __restrict__ Ws2, const float* __restrict__ bs2,
                       const int* __restrict__ ei,
                       float* __restrict__ WtT, unsigned short* __restrict__ PK,
                       float* __restrict__ bs2p, int* __restrict__ counts) {
    int idx = blockIdx.x * 256 + threadIdx.x;
    if (idx < 24576) {
        int k = idx >> 12, r = idx & 4095;
        int c = r >> 6, d = r & 63;
        const float* W = (k == 0) ? Wt0 : (k == 1) ? Wt1 : (k == 2) ? Wt2
                       : (k == 3) ? Wt3 : (k == 4) ? Wt4 : Wt5;
        WtT[idx] = W[d * 64 + c];
    } else if (idx < 26624) {            // P1: Ws0 [64 out][32 in]
        int q = idx - 24576;
        int ot = q >> 9, r = q & 511, lane = r >> 3, j = r & 7;
        int k = ((lane >> 4) * 8) + j, o = ot * 16 + (lane & 15);
        PK[q] = f2h(Ws0[o * 32 + k]);
    } else if (idx < 34816) {            // P2: Ws1 [128][64]
        int q = idx - 24576;
        int i = q - 2048, ch = i >> 9, r = i & 511, lane = r >> 3, j = r & 7;
        int ot = ch >> 1, ks = ch & 1;
        int k = ks * 32 + (lane >> 4) * 8 + j, o = ot * 16 + (lane & 15);
        PK[q] = f2h(Ws1[o * 64 + k]);
    } else if (idx < 59392) {            // P3: Ws2 [192][128], rows permuted ch'=comp*64+unit
        int q = idx - 24576;
        int i = q - 10240, ch = i >> 9, r = i & 511, lane = r >> 3, j = r & 7;
        int ot = ch >> 2, ks = ch & 3;
        int k = ks * 32 + (lane >> 4) * 8 + j;
        int op = ot * 16 + (lane & 15);
        int o = (op & 63) * 3 + (op >> 6);
        PK[q] = f2h(Ws2[o * 128 + k]);
    } else if (idx < 59584) {
        int op = idx - 59392;
        bs2p[op] = bs2[(op & 63) * 3 + (op >> 6)];
    } else if (idx < 59584 + EE) {
        int e = idx - 59584;
        atomicAdd(&counts[ei[e]], 1);
    }
}

// ---------------- CSR scan / fill ----------------
__global__ __launch_bounds__(256) void k_scan(const int* __restrict__ counts,
                                              int* __restrict__ offsets) {
    __shared__ int sums[256];
    int t = threadIdx.x;
    const int CH = 40;
    int base = t * CH;
    int s = 0;
    for (int i = 0; i < CH; i++) {
        int idx = base + i;
        if (idx < NN) s += counts[idx];
    }
    sums[t] = s;
    __syncthreads();
    for (int off = 1; off < 256; off <<= 1) {
        int tmp = (t >= off) ? sums[t - off] : 0;
        __syncthreads();
        sums[t] += tmp;
        __syncthreads();
    }
    int run = sums[t] - s;
    for (int i = 0; i < CH; i++) {
        int idx = base + i;
        if (idx < NN) { offsets[idx] = run; run += counts[idx]; }
    }
    if (t == 255) offsets[NN] = run;
}

__global__ void k_fill(const int* __restrict__ ei, const int* __restrict__ offsets,
                       int* __restrict__ cursor, int* __restrict__ bucket,
                       int* __restrict__ dstp) {
    int e = blockIdx.x * 256 + threadIdx.x;
    if (e < EE) {
        int s = ei[e];
        int pos = offsets[s] + atomicAdd(&cursor[s], 1);
        bucket[pos] = e;
        dstp[pos] = ei[EE + e];
    }
}

// ---------------- node prep: normalize, decompose, channel-linear -> IASh fp16 ----------------
__global__ __launch_bounds__(64) void k_nodeprep(const float* __restrict__ X,
                                                 const float* __restrict__ WtT,
                                                 unsigned short* __restrict__ IASh) {
    int n = blockIdx.x, c = threadIdx.x;
    __shared__ float XS[576];
    __shared__ float L[64][12];
#pragma unroll
    for (int i = 0; i < 9; i++) XS[c + 64 * i] = X[(size_t)n * 576 + c + 64 * i];
    __syncthreads();
    float x[9];
#pragma unroll
    for (int j = 0; j < 9; j++) x[j] = XS[c * 9 + j];
    float nrm = 0.f;
#pragma unroll
    for (int j = 0; j < 9; j++) nrm += x[j] * x[j];
    float inv = __builtin_amdgcn_rcpf(nrm + 1.0f);
#pragma unroll
    for (int j = 0; j < 9; j++) x[j] *= inv;
    float tr3 = (x[0] + x[4] + x[8]) * (1.0f / 3.0f);
    L[c][0] = tr3;
    L[c][1] = 0.5f * (x[1] - x[3]);
    L[c][2] = 0.5f * (x[2] - x[6]);
    L[c][3] = 0.5f * (x[5] - x[7]);
    L[c][4] = x[0] - tr3;
    L[c][5] = x[4] - tr3;
    L[c][6] = 0.5f * (x[1] + x[3]);
    L[c][7] = 0.5f * (x[2] + x[6]);
    L[c][8] = 0.5f * (x[5] + x[7]);
    __syncthreads();
    int d = c;
    const float* W0 = WtT;
    const float* W1 = WtT + 4096;
    const float* W2 = WtT + 8192;
    float aI = 0, aA0 = 0, aA1 = 0, aA2 = 0, aS0 = 0, aS1 = 0, aS2 = 0, aS3 = 0, aS4 = 0;
    for (int cc = 0; cc < 64; ++cc) {
        float w0 = W0[cc * 64 + d], w1 = W1[cc * 64 + d], w2 = W2[cc * 64 + d];
        float4 L0 = *(const float4*)&L[cc][0];
        float4 L1 = *(const float4*)&L[cc][4];
        float L8 = L[cc][8];
        aI  += w0 * L0.x;
        aA0 += w1 * L0.y; aA1 += w1 * L0.z; aA2 += w1 * L0.w;
        aS0 += w2 * L1.x; aS1 += w2 * L1.y; aS2 += w2 * L1.z;
        aS3 += w2 * L1.w; aS4 += w2 * L8;
    }
    unsigned int* op = (unsigned int*)(IASh + (size_t)n * 768 + (size_t)d * 12);
    op[0] = pkh(aI, aA0);
    op[1] = pkh(aA1, aA2);
    op[2] = pkh(aS0, aS1);
    op[3] = pkh(aS2, aS3);
    op[4] = pkh(aS4, 0.0f);
}

// ---------------- edge MLP: fp16 MFMA, swapped operands, bucket-ordered ----------------
__global__ __launch_bounds__(256) void k_mlp(const float* __restrict__ attr,
                                             const float* __restrict__ ew,
                                             const int* __restrict__ bucket,
                                             const unsigned short* __restrict__ PK,
                                             const float* __restrict__ bs0,
                                             const float* __restrict__ bs1,
                                             const float* __restrict__ bs2p,
                                             unsigned short* __restrict__ eah) {
    __shared__ unsigned short H1[64][80];    // stride 160B: b64 stores conflict-optimal
    __shared__ unsigned short H2[64][144];   // stride 288B
    int t = threadIdx.x;
    int e0 = blockIdx.x * 64;
    int l = t & 63, w = t >> 6, rb = w * 16, lr = l & 15, lg = l >> 4;
    int eid = bucket[e0 + rb + lr];
    const float* ap = attr + (size_t)eid * 32 + lg * 8;
    float4 av0 = *(const float4*)ap;
    float4 av1 = *(const float4*)(ap + 4);
    union { h16x8 h; unsigned int u[4]; } B1;
    B1.u[0] = pkh(av0.x, av0.y); B1.u[1] = pkh(av0.z, av0.w);
    B1.u[2] = pkh(av1.x, av1.y); B1.u[3] = pkh(av1.z, av1.w);
    float rw = ew[eid];
    float C = (rw < 1.0f) ? 0.5f * (cosf(3.14159265358979f * rw) + 1.0f) : 0.0f;

    const h16x8* P1 = (const h16x8*)PK;
    const h16x8* P2 = (const h16x8*)(PK + 2048);
    const h16x8* P3 = (const h16x8*)(PK + 10240);

    // layer 1: 32 -> 64 (A = weights, B = activations; D: row=channel, col=edge)
#pragma unroll
    for (int ot = 0; ot < 4; ++ot) {
        float4 bb = *(const float4*)&bs0[ot * 16 + lg * 4];
        f32x4 acc = {bb.x, bb.y, bb.z, bb.w};
        acc = __builtin_amdgcn_mfma_f32_16x16x32_f16(P1[ot * 64 + l], B1.h, acc, 0, 0, 0);
        unsigned int u01 = pkh(silu_f(acc[0]), silu_f(acc[1]));
        unsigned int u23 = pkh(silu_f(acc[2]), silu_f(acc[3]));
        *(uint2*)&H1[rb + lr][ot * 16 + lg * 4] = make_uint2(u01, u23);
    }
    __syncthreads();

    // layer 2: 64 -> 128
    h16x8 B2a = *(const h16x8*)&H1[rb + lr][lg * 8];
    h16x8 B2b = *(const h16x8*)&H1[rb + lr][32 + lg * 8];
#pragma unroll
    for (int ot = 0; ot < 8; ++ot) {
        float4 bb = *(const float4*)&bs1[ot * 16 + lg * 4];
        f32x4 acc = {bb.x, bb.y, bb.z, bb.w};
        acc = __builtin_amdgcn_mfma_f32_16x16x32_f16(P2[(ot * 2 + 0) * 64 + l], B2a, acc, 0, 0, 0);
        acc = __builtin_amdgcn_mfma_f32_16x16x32_f16(P2[(ot * 2 + 1) * 64 + l], B2b, acc, 0, 0, 0);
        unsigned int u01 = pkh(silu_f(acc[0]), silu_f(acc[1]));
        unsigned int u23 = pkh(silu_f(acc[2]), silu_f(acc[3]));
        *(uint2*)&H2[rb + lr][ot * 16 + lg * 4] = make_uint2(u01, u23);
    }
    __syncthreads();

    // layer 3: 128 -> 192 (permuted channels), scale by C, write fp16
    h16x8 B3[4];
#pragma unroll
    for (int ks = 0; ks < 4; ++ks)
        B3[ks] = *(const h16x8*)&H2[rb + lr][ks * 32 + lg * 8];
    size_t ebase = (size_t)(e0 + rb + lr) * 192;
#pragma unroll
    for (int ot = 0; ot < 12; ++ot) {
        float4 bb = *(const float4*)&bs2p[ot * 16 + lg * 4];
        f32x4 acc = {bb.x, bb.y, bb.z, bb.w};
#pragma unroll
        for (int ks = 0; ks < 4; ++ks)
            acc = __builtin_amdgcn_mfma_f32_16x16x32_f16(P3[(ot * 4 + ks) * 64 + l], B3[ks], acc, 0, 0, 0);
        unsigned int u01 = pkh(silu_f(acc[0]) * C, silu_f(acc[1]) * C);
        unsigned int u23 = pkh(silu_f(acc[2]) * C, silu_f(acc[3]) * C);
        *(uint2*)&eah[ebase + ot * 16 + lg * 4] = make_uint2(u01, u23);
    }
}

// ---------------- fused aggregation + output stage (1 wave / node) ----------------
__global__ __launch_bounds__(64) void k_aggout(const int* __restrict__ offsets,
                                               const int* __restrict__ dstp,
                                               const unsigned short* __restrict__ eah,
                                               const unsigned short* __restrict__ IASh,
                                               const float* __restrict__ X,
                                               const float* __restrict__ WtT,
                                               float* __restrict__ out) {
    int n = blockIdx.x, c = threadIdx.x;
    __shared__ float XS[576];
    __shared__ float OS[576];
    __shared__ float L[64][12];
#pragma unroll
    for (int i = 0; i < 9; i++) XS[c + 64 * i] = X[(size_t)n * 576 + c + 64 * i];
    __syncthreads();

    int beg = offsets[n], end = offsets[n + 1];
    float m0 = 0, m1 = 0, m2 = 0, m3 = 0, m4 = 0, m5 = 0, m6 = 0, m7 = 0, m8 = 0;
    for (int i = beg; i < end; ++i) {
        int dst = dstp[i];
        const unsigned short* ep = eah + (size_t)i * 192;
        float ea0 = h2f(ep[c]), ea1 = h2f(ep[64 + c]), ea2 = h2f(ep[128 + c]);
        const unsigned int* ip = (const unsigned int*)(IASh + (size_t)dst * 768 + (size_t)c * 12);
        uint2 qa = *(const uint2*)ip;
        uint2 qb = *(const uint2*)(ip + 2);
        unsigned int qc = ip[4];
        m0 += ea0 * h2f_lo(qa.x); m1 += ea1 * h2f_hi(qa.x);
        m2 += ea1 * h2f_lo(qa.y); m3 += ea1 * h2f_hi(qa.y);
        m4 += ea2 * h2f_lo(qb.x); m5 += ea2 * h2f_hi(qb.x);
        m6 += ea2 * h2f_lo(qb.y); m7 += ea2 * h2f_hi(qb.y);
        m8 += ea2 * h2f_lo(qc);
    }
    // own-node Y components from IASh
    const unsigned int* yp = (const unsigned int*)(IASh + (size_t)n * 768 + (size_t)c * 12);
    uint2 ya = *(const uint2*)yp;
    uint2 yb = *(const uint2*)(yp + 2);
    unsigned int yc = yp[4];
    float yI = h2f_lo(ya.x), yA0 = h2f_hi(ya.x), yA1 = h2f_lo(ya.y), yA2 = h2f_hi(ya.y);
    float yS0 = h2f_lo(yb.x), yS1 = h2f_hi(yb.x), yS2 = h2f_lo(yb.y), yS3 = h2f_hi(yb.y);
    float yS4 = h2f_lo(yc);

    float M[3][3] = {
        { m0 + m4,   m1 + m6,  m2 + m7 },
        { -m1 + m6,  m0 + m5,  m3 + m8 },
        { -m2 + m7, -m3 + m8,  m0 - m4 - m5 } };
    float Y[3][3] = {
        { yI + yS0,   yA0 + yS2,  yA1 + yS3 },
        { -yA0 + yS2, yI + yS1,   yA2 + yS4 },
        { -yA1 + yS3, -yA2 + yS4, yI - yS0 - yS1 } };
    float AB[3][3];
#pragma unroll
    for (int i = 0; i < 3; i++)
#pragma unroll
        for (int j = 0; j < 3; j++) {
            float s = 0.f;
#pragma unroll
            for (int k = 0; k < 3; k++) s += M[i][k] * Y[k][j] + Y[i][k] * M[k][j];
            AB[i][j] = s;
        }
    float tr3 = (AB[0][0] + AB[1][1] + AB[2][2]) * (1.0f / 3.0f);
    float fro = 0.f;
#pragma unroll
    for (int i = 0; i < 3; i++)
#pragma unroll
        for (int j = 0; j < 3; j++) fro += AB[i][j] * AB[i][j];
    float inv = __builtin_amdgcn_rcpf(fro + 1.0f);
    L[c][0] = tr3 * inv;
    L[c][1] = 0.5f * (AB[0][1] - AB[1][0]) * inv;
    L[c][2] = 0.5f * (AB[0][2] - AB[2][0]) * inv;
    L[c][3] = 0.5f * (AB[1][2] - AB[2][1]) * inv;
    L[c][4] = (AB[0][0] - tr3) * inv;
    L[c][5] = (AB[1][1] - tr3) * inv;
    L[c][6] = 0.5f * (AB[0][1] + AB[1][0]) * inv;
    L[c][7] = 0.5f * (AB[0][2] + AB[2][0]) * inv;
    L[c][8] = 0.5f * (AB[1][2] + AB[2][1]) * inv;
    __syncthreads();
    int d = c;
    const float* W3 = WtT + 3 * 4096;
    const float* W4 = WtT + 4 * 4096;
    const float* W5 = WtT + 5 * 4096;
    float aI = 0, aA0 = 0, aA1 = 0, aA2 = 0, aS0 = 0, aS1 = 0, aS2 = 0, aS3 = 0, aS4 = 0;
    for (int cc = 0; cc < 64; ++cc) {
        float w3 = W3[cc * 64 + d], w4 = W4[cc * 64 + d], w5 = W5[cc * 64 + d];
        float4 L0 = *(const float4*)&L[cc][0];
        float4 L1 = *(const float4*)&L[cc][4];
        float L8 = L[cc][8];
        aI  += w3 * L0.x;
        aA0 += w4 * L0.y; aA1 += w4 * L0.z; aA2 += w4 * L0.w;
        aS0 += w5 * L1.x; aS1 += w5 * L1.y; aS2 += w5 * L1.z;
        aS3 += w5 * L1.w; aS4 += w5 * L8;
    }
    float dX[3][3] = {
        { aI + aS0,   aA0 + aS2,  aA1 + aS3 },
        { -aA0 + aS2, aI + aS1,   aA2 + aS4 },
        { -aA1 + aS3, -aA2 + aS4, aI - aS0 - aS1 } };
    float D2[3][3];
#pragma unroll
    for (int i = 0; i < 3; i++)
#pragma unroll
        for (int j = 0; j < 3; j++) {
            float s = 0.f;
#pragma unroll
            for (int k = 0; k < 3; k++) s += dX[i][k] * dX[k][j];
            D2[i][j] = s;
        }
    // normalized X (recomputed, matches reference)
    float x[9];
#pragma unroll
    for (int j = 0; j < 9; j++) x[j] = XS[d * 9 + j];
    float nrm = 0.f;
#pragma unroll
    for (int j = 0; j < 9; j++) nrm += x[j] * x[j];
    float xinv = __builtin_amdgcn_rcpf(nrm + 1.0f);
#pragma unroll
    for (int i = 0; i < 3; i++)
#pragma unroll
        for (int j = 0; j < 3; j++)
            OS[d * 9 + i * 3 + j] = x[i * 3 + j] * xinv + dX[i][j] + D2[i][j];
    __syncthreads();
#pragma unroll
    for (int i = 0; i < 9; i++) out[(size_t)n * 576 + c + 64 * i] = OS[c + 64 * i];
}

extern "C" void kernel_launch(void* const* d_in, const int* in_sizes, int n_in,
                              void* d_out, int out_size, void* d_ws, size_t ws_size,
                              hipStream_t stream) {
    (void)in_sizes; (void)n_in; (void)out_size; (void)ws_size;
    const int* ei = (const int*)d_in[0];
    const float* ew = (const float*)d_in[1];
    const float* attr = (const float*)d_in[2];
    const float* X = (const float*)d_in[3];
    const float* Ws0 = (const float*)d_in[4];
    const float* bs0 = (const float*)d_in[5];
    const float* Ws1 = (const float*)d_in[6];
    const float* bs1 = (const float*)d_in[7];
    const float* Ws2 = (const float*)d_in[8];
    const float* bs2 = (const float*)d_in[9];
    const float* Wt0 = (const float*)d_in[10];
    const float* Wt1 = (const float*)d_in[11];
    const float* Wt2 = (const float*)d_in[12];
    const float* Wt3 = (const float*)d_in[13];
    const float* Wt4 = (const float*)d_in[14];
    const float* Wt5 = (const float*)d_in[15];
    float* ws = (float*)d_ws;
    int* ibase = (int*)(ws + OFF_INT);
    int* counts = ibase;
    int* cursor = ibase + NN;
    int* offsets = ibase + 2 * NN;
    int* bucket = ibase + 3 * NN + 1;
    int* dstp = bucket + EE;
    unsigned short* PK = (unsigned short*)(ws + OFF_PK);
    unsigned short* IASh = (unsigned short*)(ws + OFF_IASH);
    unsigned short* eah = (unsigned short*)(ws + OFF_EAH);

    (void)hipMemsetAsync(counts, 0, 2 * NN * sizeof(int), stream);
    k_prep<<<(59584 + EE + 255) / 256, 256, 0, stream>>>(
        Wt0, Wt1, Wt2, Wt3, Wt4, Wt5, Ws0, Ws1, Ws2, bs2, ei,
        ws, PK, ws + OFF_B2P, counts);
    k_scan<<<1, 256, 0, stream>>>(counts, offsets);
    k_fill<<<(EE + 255) / 256, 256, 0, stream>>>(ei, offsets, cursor, bucket, dstp);
    k_nodeprep<<<NN, 64, 0, stream>>>(X, ws, IASh);
    k_mlp<<<EE / 64, 256, 0, stream>>>(attr, ew, bucket, PK, bs0, bs1, ws + OFF_B2P, eah);
    k_aggout<<<NN, 64, 0, stream>>>(offsets, dstp, eah, IASh, X, ws, (float*)d_out);
}

// Round 6
// 162.815 us; speedup vs baseline: 6.6346x; 1.1406x over previous
//
#include <hip/hip_runtime.h>
#include <math.h>

#define NN 10000
#define EE 160000

// ---- workspace layout (float indices) ----
#define OFF_WTT 0            // [6][64][64] f32 (WtT[k][c][d] = Wt_k[d][c])   len 24576
#define OFF_PK  24576        // packed f16 MLP weights, 34816 u16             len 17408
#define OFF_B2P 41984        // permuted bs2 f32 [192]                        len 192
#define OFF_IASH 42176       // [N][5][64] u32 packed fp16 pairs              len 3200000
#define OFF_EAH 3242176      // [E][192] f16, ch' = comp*64+unit              len 15360000
#define OFF_INT 18602176     // counts[N] cursor[N] offsets[N+1] bucket[E] dstp[E]

typedef __attribute__((ext_vector_type(8))) _Float16 h16x8;
typedef __attribute__((ext_vector_type(2))) __fp16 fp16x2_raw;
typedef __attribute__((ext_vector_type(4))) float f32x4;

__device__ __forceinline__ float silu_f(float x) {
    return x * __builtin_amdgcn_rcpf(1.0f + __expf(-x));
}
__device__ __forceinline__ unsigned int pkh(float a, float b) {
    union { fp16x2_raw h; unsigned int u; } cv;
    cv.h = __builtin_amdgcn_cvt_pkrtz(a, b);
    return cv.u;
}
__device__ __forceinline__ unsigned short f2h(float f) {
    union { _Float16 h; unsigned short u; } cv; cv.h = (_Float16)f; return cv.u;
}
__device__ __forceinline__ float h2f(unsigned short s) {
    union { unsigned short u; _Float16 h; } cv; cv.u = s; return (float)cv.h;
}
__device__ __forceinline__ float h2f_lo(unsigned int u) { return h2f((unsigned short)(u & 0xffffu)); }
__device__ __forceinline__ float h2f_hi(unsigned int u) { return h2f((unsigned short)(u >> 16)); }

// ---------------- prep: Wt transpose + f16 weight pack + bs2 permute + degree count ----------------
__global__ void k_prep(const float* __restrict__ Wt0, const float* __restrict__ Wt1,
                       const float* __restrict__ Wt2, const float* __restrict__ Wt3,
                       const float* __restrict__ Wt4, const float* __restrict__ Wt5,
                       const float* __restrict__ Ws0, const float* __restrict__ Ws1,
                       const float* __restrict__ Ws2, const float* __restrict__ bs2,
                       const int* __restrict__ ei,
                       float* __restrict__ WtT, unsigned short* __restrict__ PK,
                       float* __restrict__ bs2p, int* __restrict__ counts) {
    int idx = blockIdx.x * 256 + threadIdx.x;
    if (idx < 24576) {
        int k = idx >> 12, r = idx & 4095;
        int c = r >> 6, d = r & 63;
        const float* W = (k == 0) ? Wt0 : (k == 1) ? Wt1 : (k == 2) ? Wt2
                       : (k == 3) ? Wt3 : (k == 4) ? Wt4 : Wt5;
        WtT[idx] = W[d * 64 + c];
    } else if (idx < 26624) {            // P1: Ws0 [64 out][32 in]
        int q = idx - 24576;
        int ot = q >> 9, r = q & 511, lane = r >> 3, j = r & 7;
        int k = ((lane >> 4) * 8) + j, o = ot * 16 + (lane & 15);
        PK[q] = f2h(Ws0[o * 32 + k]);
    } else if (idx < 34816) {            // P2: Ws1 [128][64]
        int q = idx - 24576;
        int i = q - 2048, ch = i >> 9, r = i & 511, lane = r >> 3, j = r & 7;
        int ot = ch >> 1, ks = ch & 1;
        int k = ks * 32 + (lane >> 4) * 8 + j, o = ot * 16 + (lane & 15);
        PK[q] = f2h(Ws1[o * 64 + k]);
    } else if (idx < 59392) {            // P3: Ws2 [192][128], rows permuted ch'=comp*64+unit
        int q = idx - 24576;
        int i = q - 10240, ch = i >> 9, r = i & 511, lane = r >> 3, j = r & 7;
        int ot = ch >> 2, ks = ch & 3;
        int k = ks * 32 + (lane >> 4) * 8 + j;
        int op = ot * 16 + (lane & 15);
        int o = (op & 63) * 3 + (op >> 6);
        PK[q] = f2h(Ws2[o * 128 + k]);
    } else if (idx < 59584) {
        int op = idx - 59392;
        bs2p[op] = bs2[(op & 63) * 3 + (op >> 6)];
    } else if (idx < 59584 + EE) {
        int e = idx - 59584;
        atomicAdd(&counts[ei[e]], 1);
    }
}

// ---------------- CSR scan / fill ----------------
__global__ __launch_bounds__(256) void k_scan(const int* __restrict__ counts,
                                              int* __restrict__ offsets) {
    __shared__ int sums[256];
    int t = threadIdx.x;
    int base = t * 40;                    // 250 * 40 = 10000 exactly
    int s = 0;
    if (base < NN) {
        const int4* p = (const int4*)(counts + base);
#pragma unroll
        for (int q = 0; q < 10; ++q) { int4 a = p[q]; s += a.x + a.y + a.z + a.w; }
    }
    sums[t] = s;
    __syncthreads();
    for (int off = 1; off < 256; off <<= 1) {
        int tmp = (t >= off) ? sums[t - off] : 0;
        __syncthreads();
        sums[t] += tmp;
        __syncthreads();
    }
    int run = sums[t] - s;
    if (base < NN) {
        const int4* p = (const int4*)(counts + base);
#pragma unroll
        for (int q = 0; q < 10; ++q) {
            int4 a = p[q];
            offsets[base + 4 * q + 0] = run; run += a.x;
            offsets[base + 4 * q + 1] = run; run += a.y;
            offsets[base + 4 * q + 2] = run; run += a.z;
            offsets[base + 4 * q + 3] = run; run += a.w;
        }
    }
    if (t == 255) offsets[NN] = run;
}

__global__ void k_fill(const int* __restrict__ ei, const int* __restrict__ offsets,
                       int* __restrict__ cursor, int* __restrict__ bucket,
                       int* __restrict__ dstp) {
    int e = blockIdx.x * 256 + threadIdx.x;
    if (e < EE) {
        int s = ei[e];
        int pos = offsets[s] + atomicAdd(&cursor[s], 1);
        bucket[pos] = e;
        dstp[pos] = ei[EE + e];
    }
}

// ---------------- node prep: 4 nodes/block, 1 wave/node, no barriers ----------------
__global__ __launch_bounds__(256) void k_nodeprep(const float* __restrict__ X,
                                                  const float* __restrict__ WtT,
                                                  unsigned int* __restrict__ IASu) {
    int t = threadIdx.x, w = t >> 6, c = t & 63;
    int n = blockIdx.x * 4 + w;
    __shared__ float XS[4][576];
    __shared__ float L[4][64][12];
    float* xs = XS[w];
#pragma unroll
    for (int i = 0; i < 9; i++) xs[c + 64 * i] = X[(size_t)n * 576 + c + 64 * i];
    __builtin_amdgcn_wave_barrier();
    float x[9];
#pragma unroll
    for (int j = 0; j < 9; j++) x[j] = xs[c * 9 + j];
    float nrm = 0.f;
#pragma unroll
    for (int j = 0; j < 9; j++) nrm += x[j] * x[j];
    float inv = __builtin_amdgcn_rcpf(nrm + 1.0f);
#pragma unroll
    for (int j = 0; j < 9; j++) x[j] *= inv;
    float tr3 = (x[0] + x[4] + x[8]) * (1.0f / 3.0f);
    L[w][c][0] = tr3;
    L[w][c][1] = 0.5f * (x[1] - x[3]);
    L[w][c][2] = 0.5f * (x[2] - x[6]);
    L[w][c][3] = 0.5f * (x[5] - x[7]);
    L[w][c][4] = x[0] - tr3;
    L[w][c][5] = x[4] - tr3;
    L[w][c][6] = 0.5f * (x[1] + x[3]);
    L[w][c][7] = 0.5f * (x[2] + x[6]);
    L[w][c][8] = 0.5f * (x[5] + x[7]);
    __builtin_amdgcn_wave_barrier();
    int d = c;
    const float* W0 = WtT;
    const float* W1 = WtT + 4096;
    const float* W2 = WtT + 8192;
    float aI = 0, aA0 = 0, aA1 = 0, aA2 = 0, aS0 = 0, aS1 = 0, aS2 = 0, aS3 = 0, aS4 = 0;
    for (int cc = 0; cc < 64; ++cc) {
        float w0 = W0[cc * 64 + d], w1 = W1[cc * 64 + d], w2 = W2[cc * 64 + d];
        float4 L0 = *(const float4*)&L[w][cc][0];
        float4 L1 = *(const float4*)&L[w][cc][4];
        float L8 = L[w][cc][8];
        aI  += w0 * L0.x;
        aA0 += w1 * L0.y; aA1 += w1 * L0.z; aA2 += w1 * L0.w;
        aS0 += w2 * L1.x; aS1 += w2 * L1.y; aS2 += w2 * L1.z;
        aS3 += w2 * L1.w; aS4 += w2 * L8;
    }
    unsigned int* op = IASu + (size_t)n * 320 + d;
    op[0]   = pkh(aI, aA0);
    op[64]  = pkh(aA1, aA2);
    op[128] = pkh(aS0, aS1);
    op[192] = pkh(aS2, aS3);
    op[256] = pkh(aS4, 0.0f);
}

// ---------------- edge MLP: fp16 MFMA, per-wave LDS, no barriers ----------------
__global__ __launch_bounds__(256) void k_mlp(const float* __restrict__ attr,
                                             const float* __restrict__ ew,
                                             const int* __restrict__ bucket,
                                             const unsigned short* __restrict__ PK,
                                             const float* __restrict__ bs0,
                                             const float* __restrict__ bs1,
                                             const float* __restrict__ bs2p,
                                             unsigned short* __restrict__ eah) {
    __shared__ unsigned short H[4][16][152];   // per-wave [16 edges][152]; L1 out 0..63, L2 out 0..127
    int t = threadIdx.x;
    int l = t & 63, w = t >> 6, lr = l & 15, lg = l >> 4;
    int pos = blockIdx.x * 64 + w * 16 + lr;
    int eid = bucket[pos];
    const float* ap = attr + (size_t)eid * 32 + lg * 8;
    float4 av0 = *(const float4*)ap;
    float4 av1 = *(const float4*)(ap + 4);
    union { h16x8 h; unsigned int u[4]; } B1;
    B1.u[0] = pkh(av0.x, av0.y); B1.u[1] = pkh(av0.z, av0.w);
    B1.u[2] = pkh(av1.x, av1.y); B1.u[3] = pkh(av1.z, av1.w);
    float rw = ew[eid];
    float C = (rw < 1.0f) ? 0.5f * (cosf(3.14159265358979f * rw) + 1.0f) : 0.0f;

    const h16x8* P1 = (const h16x8*)PK;
    const h16x8* P2 = (const h16x8*)(PK + 2048);
    const h16x8* P3 = (const h16x8*)(PK + 10240);

    // layer 1: 32 -> 64 (A = weights, B = activations; lane holds edge lr, channels ot*16+lg*4..+3)
#pragma unroll
    for (int ot = 0; ot < 4; ++ot) {
        float4 bb = *(const float4*)&bs0[ot * 16 + lg * 4];
        f32x4 acc = {bb.x, bb.y, bb.z, bb.w};
        acc = __builtin_amdgcn_mfma_f32_16x16x32_f16(P1[ot * 64 + l], B1.h, acc, 0, 0, 0);
        unsigned int u01 = pkh(silu_f(acc[0]), silu_f(acc[1]));
        unsigned int u23 = pkh(silu_f(acc[2]), silu_f(acc[3]));
        *(uint2*)&H[w][lr][ot * 16 + lg * 4] = make_uint2(u01, u23);
    }
    __builtin_amdgcn_wave_barrier();

    // layer 2: 64 -> 128 (B-fragments reg-resident before overwriting H)
    h16x8 B2a = *(const h16x8*)&H[w][lr][lg * 8];
    h16x8 B2b = *(const h16x8*)&H[w][lr][32 + lg * 8];
    __builtin_amdgcn_wave_barrier();
#pragma unroll
    for (int ot = 0; ot < 8; ++ot) {
        float4 bb = *(const float4*)&bs1[ot * 16 + lg * 4];
        f32x4 acc = {bb.x, bb.y, bb.z, bb.w};
        acc = __builtin_amdgcn_mfma_f32_16x16x32_f16(P2[(ot * 2 + 0) * 64 + l], B2a, acc, 0, 0, 0);
        acc = __builtin_amdgcn_mfma_f32_16x16x32_f16(P2[(ot * 2 + 1) * 64 + l], B2b, acc, 0, 0, 0);
        unsigned int u01 = pkh(silu_f(acc[0]), silu_f(acc[1]));
        unsigned int u23 = pkh(silu_f(acc[2]), silu_f(acc[3]));
        *(uint2*)&H[w][lr][ot * 16 + lg * 4] = make_uint2(u01, u23);
    }
    __builtin_amdgcn_wave_barrier();

    // layer 3: 128 -> 192 (permuted channels), scale by C, write fp16
    h16x8 B3[4];
#pragma unroll
    for (int ks = 0; ks < 4; ++ks)
        B3[ks] = *(const h16x8*)&H[w][lr][ks * 32 + lg * 8];
    size_t ebase = (size_t)pos * 192;
#pragma unroll
    for (int ot = 0; ot < 12; ++ot) {
        float4 bb = *(const float4*)&bs2p[ot * 16 + lg * 4];
        f32x4 acc = {bb.x, bb.y, bb.z, bb.w};
#pragma unroll
        for (int ks = 0; ks < 4; ++ks)
            acc = __builtin_amdgcn_mfma_f32_16x16x32_f16(P3[(ot * 4 + ks) * 64 + l], B3[ks], acc, 0, 0, 0);
        unsigned int u01 = pkh(silu_f(acc[0]) * C, silu_f(acc[1]) * C);
        unsigned int u23 = pkh(silu_f(acc[2]) * C, silu_f(acc[3]) * C);
        *(uint2*)&eah[ebase + ot * 16 + lg * 4] = make_uint2(u01, u23);
    }
}

// ---------------- fused aggregation + output: 4 nodes/block, 1 wave/node ----------------
__global__ __launch_bounds__(256) void k_aggout(const int* __restrict__ offsets,
                                                const int* __restrict__ dstp,
                                                const unsigned short* __restrict__ eah,
                                                const unsigned int* __restrict__ IASu,
                                                const float* __restrict__ X,
                                                const float* __restrict__ WtT,
                                                float* __restrict__ out) {
    int t = threadIdx.x, w = t >> 6, c = t & 63;
    int n = blockIdx.x * 4 + w;
    __shared__ float XS[4][576];
    __shared__ float LO[4][768];      // L [64][12] then reused as OS [576]
    float* xs = XS[w];
    float* lo = LO[w];
#pragma unroll
    for (int i = 0; i < 9; i++) xs[c + 64 * i] = X[(size_t)n * 576 + c + 64 * i];

    int beg = offsets[n], end = offsets[n + 1];
    float m0 = 0, m1 = 0, m2 = 0, m3 = 0, m4 = 0, m5 = 0, m6 = 0, m7 = 0, m8 = 0;
    int i = beg;
    for (; i + 2 <= end; i += 2) {
        int d0 = dstp[i], d1 = dstp[i + 1];
        const unsigned short* ep0 = eah + (size_t)i * 192;
        const unsigned short* ep1 = ep0 + 192;
        float a00 = h2f(ep0[c]), a01 = h2f(ep0[64 + c]), a02 = h2f(ep0[128 + c]);
        float a10 = h2f(ep1[c]), a11 = h2f(ep1[64 + c]), a12 = h2f(ep1[128 + c]);
        const unsigned int* p0 = IASu + (size_t)d0 * 320 + c;
        const unsigned int* p1 = IASu + (size_t)d1 * 320 + c;
        unsigned int u00 = p0[0], u01 = p0[64], u02 = p0[128], u03 = p0[192], u04 = p0[256];
        unsigned int u10 = p1[0], u11 = p1[64], u12 = p1[128], u13 = p1[192], u14 = p1[256];
        m0 += a00 * h2f_lo(u00) + a10 * h2f_lo(u10);
        m1 += a01 * h2f_hi(u00) + a11 * h2f_hi(u10);
        m2 += a01 * h2f_lo(u01) + a11 * h2f_lo(u11);
        m3 += a01 * h2f_hi(u01) + a11 * h2f_hi(u11);
        m4 += a02 * h2f_lo(u02) + a12 * h2f_lo(u12);
        m5 += a02 * h2f_hi(u02) + a12 * h2f_hi(u12);
        m6 += a02 * h2f_lo(u03) + a12 * h2f_lo(u13);
        m7 += a02 * h2f_hi(u03) + a12 * h2f_hi(u13);
        m8 += a02 * h2f_lo(u04) + a12 * h2f_lo(u14);
    }
    if (i < end) {
        int d0 = dstp[i];
        const unsigned short* ep0 = eah + (size_t)i * 192;
        float a00 = h2f(ep0[c]), a01 = h2f(ep0[64 + c]), a02 = h2f(ep0[128 + c]);
        const unsigned int* p0 = IASu + (size_t)d0 * 320 + c;
        unsigned int u00 = p0[0], u01 = p0[64], u02 = p0[128], u03 = p0[192], u04 = p0[256];
        m0 += a00 * h2f_lo(u00); m1 += a01 * h2f_hi(u00);
        m2 += a01 * h2f_lo(u01); m3 += a01 * h2f_hi(u01);
        m4 += a02 * h2f_lo(u02); m5 += a02 * h2f_hi(u02);
        m6 += a02 * h2f_lo(u03); m7 += a02 * h2f_hi(u03);
        m8 += a02 * h2f_lo(u04);
    }
    // own-node Y
    const unsigned int* yp = IASu + (size_t)n * 320 + c;
    unsigned int y0 = yp[0], y1 = yp[64], y2 = yp[128], y3 = yp[192], y4 = yp[256];
    float yI = h2f_lo(y0), yA0 = h2f_hi(y0), yA1 = h2f_lo(y1), yA2 = h2f_hi(y1);
    float yS0 = h2f_lo(y2), yS1 = h2f_hi(y2), yS2 = h2f_lo(y3), yS3 = h2f_hi(y3);
    float yS4 = h2f_lo(y4);

    float M[3][3] = {
        { m0 + m4,   m1 + m6,  m2 + m7 },
        { -m1 + m6,  m0 + m5,  m3 + m8 },
        { -m2 + m7, -m3 + m8,  m0 - m4 - m5 } };
    float Y[3][3] = {
        { yI + yS0,   yA0 + yS2,  yA1 + yS3 },
        { -yA0 + yS2, yI + yS1,   yA2 + yS4 },
        { -yA1 + yS3, -yA2 + yS4, yI - yS0 - yS1 } };
    float AB[3][3];
#pragma unroll
    for (int ii = 0; ii < 3; ii++)
#pragma unroll
        for (int j = 0; j < 3; j++) {
            float s = 0.f;
#pragma unroll
            for (int k = 0; k < 3; k++) s += M[ii][k] * Y[k][j] + Y[ii][k] * M[k][j];
            AB[ii][j] = s;
        }
    float tr3 = (AB[0][0] + AB[1][1] + AB[2][2]) * (1.0f / 3.0f);
    float fro = 0.f;
#pragma unroll
    for (int ii = 0; ii < 3; ii++)
#pragma unroll
        for (int j = 0; j < 3; j++) fro += AB[ii][j] * AB[ii][j];
    float inv = __builtin_amdgcn_rcpf(fro + 1.0f);
    float (*L12)[12] = (float (*)[12])lo;
    L12[c][0] = tr3 * inv;
    L12[c][1] = 0.5f * (AB[0][1] - AB[1][0]) * inv;
    L12[c][2] = 0.5f * (AB[0][2] - AB[2][0]) * inv;
    L12[c][3] = 0.5f * (AB[1][2] - AB[2][1]) * inv;
    L12[c][4] = (AB[0][0] - tr3) * inv;
    L12[c][5] = (AB[1][1] - tr3) * inv;
    L12[c][6] = 0.5f * (AB[0][1] + AB[1][0]) * inv;
    L12[c][7] = 0.5f * (AB[0][2] + AB[2][0]) * inv;
    L12[c][8] = 0.5f * (AB[1][2] + AB[2][1]) * inv;
    __builtin_amdgcn_wave_barrier();
    int d = c;
    const float* W3 = WtT + 3 * 4096;
    const float* W4 = WtT + 4 * 4096;
    const float* W5 = WtT + 5 * 4096;
    float aI = 0, aA0 = 0, aA1 = 0, aA2 = 0, aS0 = 0, aS1 = 0, aS2 = 0, aS3 = 0, aS4 = 0;
    for (int cc = 0; cc < 64; ++cc) {
        float w3 = W3[cc * 64 + d], w4 = W4[cc * 64 + d], w5 = W5[cc * 64 + d];
        float4 L0 = *(const float4*)&L12[cc][0];
        float4 L1 = *(const float4*)&L12[cc][4];
        float L8 = L12[cc][8];
        aI  += w3 * L0.x;
        aA0 += w4 * L0.y; aA1 += w4 * L0.z; aA2 += w4 * L0.w;
        aS0 += w5 * L1.x; aS1 += w5 * L1.y; aS2 += w5 * L1.z;
        aS3 += w5 * L1.w; aS4 += w5 * L8;
    }
    float dX[3][3] = {
        { aI + aS0,   aA0 + aS2,  aA1 + aS3 },
        { -aA0 + aS2, aI + aS1,   aA2 + aS4 },
        { -aA1 + aS3, -aA2 + aS4, aI - aS0 - aS1 } };
    float D2[3][3];
#pragma unroll
    for (int ii = 0; ii < 3; ii++)
#pragma unroll
        for (int j = 0; j < 3; j++) {
            float s = 0.f;
#pragma unroll
            for (int k = 0; k < 3; k++) s += dX[ii][k] * dX[k][j];
            D2[ii][j] = s;
        }
    float x[9];
    __builtin_amdgcn_wave_barrier();
#pragma unroll
    for (int j = 0; j < 9; j++) x[j] = xs[d * 9 + j];
    float nrm = 0.f;
#pragma unroll
    for (int j = 0; j < 9; j++) nrm += x[j] * x[j];
    float xinv = __builtin_amdgcn_rcpf(nrm + 1.0f);
    // overwrite lo (L dead) with output staging
    __builtin_amdgcn_wave_barrier();
#pragma unroll
    for (int ii = 0; ii < 3; ii++)
#pragma unroll
        for (int j = 0; j < 3; j++)
            lo[d * 9 + ii * 3 + j] = x[ii * 3 + j] * xinv + dX[ii][j] + D2[ii][j];
    __builtin_amdgcn_wave_barrier();
#pragma unroll
    for (int ii = 0; ii < 9; ii++) out[(size_t)n * 576 + c + 64 * ii] = lo[c + 64 * ii];
}

extern "C" void kernel_launch(void* const* d_in, const int* in_sizes, int n_in,
                              void* d_out, int out_size, void* d_ws, size_t ws_size,
                              hipStream_t stream) {
    (void)in_sizes; (void)n_in; (void)out_size; (void)ws_size;
    const int* ei = (const int*)d_in[0];
    const float* ew = (const float*)d_in[1];
    const float* attr = (const float*)d_in[2];
    const float* X = (const float*)d_in[3];
    const float* Ws0 = (const float*)d_in[4];
    const float* bs0 = (const float*)d_in[5];
    const float* Ws1 = (const float*)d_in[6];
    const float* bs1 = (const float*)d_in[7];
    const float* Ws2 = (const float*)d_in[8];
    const float* bs2 = (const float*)d_in[9];
    const float* Wt0 = (const float*)d_in[10];
    const float* Wt1 = (const float*)d_in[11];
    const float* Wt2 = (const float*)d_in[12];
    const float* Wt3 = (const float*)d_in[13];
    const float* Wt4 = (const float*)d_in[14];
    const float* Wt5 = (const float*)d_in[15];
    float* ws = (float*)d_ws;
    int* ibase = (int*)(ws + OFF_INT);
    int* counts = ibase;
    int* cursor = ibase + NN;
    int* offsets = ibase + 2 * NN;
    int* bucket = ibase + 3 * NN + 1;
    int* dstp = bucket + EE;
    unsigned short* PK = (unsigned short*)(ws + OFF_PK);
    unsigned int* IASu = (unsigned int*)(ws + OFF_IASH);
    unsigned short* eah = (unsigned short*)(ws + OFF_EAH);

    (void)hipMemsetAsync(counts, 0, 2 * NN * sizeof(int), stream);
    k_prep<<<(59584 + EE + 255) / 256, 256, 0, stream>>>(
        Wt0, Wt1, Wt2, Wt3, Wt4, Wt5, Ws0, Ws1, Ws2, bs2, ei,
        ws, PK, ws + OFF_B2P, counts);
    k_scan<<<1, 256, 0, stream>>>(counts, offsets);
    k_fill<<<(EE + 255) / 256, 256, 0, stream>>>(ei, offsets, cursor, bucket, dstp);
    k_nodeprep<<<NN / 4, 256, 0, stream>>>(X, ws, IASu);
    k_mlp<<<EE / 64, 256, 0, stream>>>(attr, ew, bucket, PK, bs0, bs1, ws + OFF_B2P, eah);
    k_aggout<<<NN / 4, 256, 0, stream>>>(offsets, dstp, eah, IASu, X, ws, (float*)d_out);
}